// Round 1
// baseline (3517.401 us; speedup 1.0000x reference)
//
#include <hip/hip_runtime.h>
#include <math.h>

// Problem constants (from reference)
constexpr int NN = 100000;   // nodes
constexpr int NE = 1600000;  // edges
constexpr int H  = 128;      // feat/hidden
constexpr int NG = 100;      // graphs
constexpr int NC = 10;       // classes

// ---------- degree / norm ----------
__global__ void k_deg(const int* __restrict__ dst, float* __restrict__ deg) {
    int e = blockIdx.x * 256 + threadIdx.x;
    if (e < NE) atomicAdd(&deg[dst[e]], 1.0f);
}

__global__ void k_dis(float* __restrict__ deg) {
    int i = blockIdx.x * 256 + threadIdx.x;
    if (i < NN) deg[i] = rsqrtf(deg[i] + 1.0f);  // +1 self loop; in-place -> deg_inv_sqrt
}

// ---------- GEMM: Y[n,128] = X[n,128] @ W[128,128] ----------
// Tile: 16 rows x 128 cols per block (256 threads), micro-tile 2x4 per thread.
__global__ __launch_bounds__(256) void k_gemm(const float* __restrict__ X,
                                              const float* __restrict__ W,
                                              float* __restrict__ Y) {
    __shared__ __align__(16) float Ws[H][H];       // 64 KB
    __shared__ __align__(16) float Xs[16][H + 4];  // pad to dodge bank conflicts
    int tid = threadIdx.x;
    for (int i = tid; i < H * H; i += 256) Ws[i >> 7][i & 127] = W[i];
    int row0 = blockIdx.x * 16;
    for (int i = tid; i < 16 * H; i += 256)
        Xs[i >> 7][i & 127] = X[(row0 + (i >> 7)) * H + (i & 127)];
    __syncthreads();

    int cx = tid & 31;   // col group: cols cx*4 .. cx*4+3
    int ry = tid >> 5;   // row group: rows ry*2, ry*2+1
    float a00 = 0.f, a01 = 0.f, a02 = 0.f, a03 = 0.f;
    float a10 = 0.f, a11 = 0.f, a12 = 0.f, a13 = 0.f;
    #pragma unroll 4
    for (int k = 0; k < H; k++) {
        float4 w = *(const float4*)&Ws[k][cx * 4];
        float x0 = Xs[ry * 2][k];
        float x1 = Xs[ry * 2 + 1][k];
        a00 += x0 * w.x; a01 += x0 * w.y; a02 += x0 * w.z; a03 += x0 * w.w;
        a10 += x1 * w.x; a11 += x1 * w.y; a12 += x1 * w.z; a13 += x1 * w.w;
    }
    float4 v0 = make_float4(a00, a01, a02, a03);
    float4 v1 = make_float4(a10, a11, a12, a13);
    *(float4*)&Y[(row0 + ry * 2 + 0) * H + cx * 4] = v0;
    *(float4*)&Y[(row0 + ry * 2 + 1) * H + cx * 4] = v1;
}

// ---------- agg init: agg = h * dis^2 + b ----------
__global__ void k_init_agg(const float* __restrict__ h, const float* __restrict__ dis,
                           const float* __restrict__ b, float* __restrict__ agg) {
    int idx = blockIdx.x * 256 + threadIdx.x;  // NN*H divisible by 256
    int node = idx >> 7, f = idx & 127;
    float d = dis[node];
    agg[idx] = h[idx] * d * d + b[f];
}

// ---------- edge scatter: agg[dst] += h[src] * dis[src]*dis[dst] ----------
__global__ __launch_bounds__(256) void k_scatter(const float* __restrict__ h,
                                                 const int* __restrict__ src,
                                                 const int* __restrict__ dst,
                                                 const float* __restrict__ dis,
                                                 float* __restrict__ agg) {
    int e = blockIdx.x * 2 + (threadIdx.x >> 7);  // NE even; grid = NE/2 exactly
    int f = threadIdx.x & 127;
    int s = src[e], d = dst[e];
    float nrm = dis[s] * dis[d];
    atomicAdd(&agg[d * H + f], h[s * H + f] * nrm);
}

// ---------- BN column stats ----------
__global__ void k_stats(const float* __restrict__ x, float* __restrict__ sums) {
    int f = threadIdx.x;  // 128 threads
    float s = 0.f, s2 = 0.f;
    for (int r = blockIdx.x; r < NN; r += gridDim.x) {
        float v = x[r * H + f];
        s += v; s2 += v * v;
    }
    atomicAdd(&sums[f], s);
    atomicAdd(&sums[128 + f], s2);
}

__global__ void k_scaleshift(const float* __restrict__ sums, const float* __restrict__ gamma,
                             const float* __restrict__ beta, float* __restrict__ ss) {
    int f = threadIdx.x;  // 128
    float mean = sums[f] * (1.0f / NN);
    float var  = sums[128 + f] * (1.0f / NN) - mean * mean;
    float sc   = gamma[f] * rsqrtf(var + 1e-5f);
    ss[f] = sc;
    ss[128 + f] = beta[f] - mean * sc;
}

__global__ void k_bnrelu(const float* __restrict__ agg, const float* __restrict__ ss,
                         float* __restrict__ out) {
    int idx = blockIdx.x * 256 + threadIdx.x;
    int f = idx & 127;
    float v = agg[idx] * ss[f] + ss[128 + f];
    out[idx] = v > 0.f ? v : 0.f;
}

// ---------- global mean pool (sum + counts) ----------
__global__ void k_pool(const float* __restrict__ x, const int* __restrict__ batch,
                       float* __restrict__ pooled, float* __restrict__ counts) {
    int idx = blockIdx.x * 256 + threadIdx.x;
    int node = idx >> 7, f = idx & 127;
    int g = batch[node];
    atomicAdd(&pooled[g * H + f], x[idx]);
    if (f == 0) atomicAdd(&counts[g], 1.0f);
}

// ---------- MLP head + log_softmax ----------
__global__ __launch_bounds__(128) void k_head(const float* __restrict__ pooled,
                                              const float* __restrict__ counts,
                                              const float* __restrict__ w1, const float* __restrict__ b1,
                                              const float* __restrict__ w2, const float* __restrict__ b2,
                                              float* __restrict__ out) {
    __shared__ float p[H], hh[H], lg[NC], red;
    int g = blockIdx.x, f = threadIdx.x;
    float cnt = counts[g]; cnt = cnt > 1.f ? cnt : 1.f;
    p[f] = pooled[g * H + f] / cnt;
    __syncthreads();
    float a = b1[f];
    for (int k = 0; k < H; k++) a += p[k] * w1[k * H + f];
    hh[f] = a > 0.f ? a : 0.f;
    __syncthreads();
    if (f < NC) {
        float l = b2[f];
        for (int k = 0; k < H; k++) l += hh[k] * w2[k * NC + f];
        lg[f] = l;
    }
    __syncthreads();
    if (f == 0) {
        float m = lg[0];
        for (int c = 1; c < NC; c++) m = m > lg[c] ? m : lg[c];
        float s = 0.f;
        for (int c = 0; c < NC; c++) s += expf(lg[c] - m);
        red = m + logf(s);
    }
    __syncthreads();
    if (f < NC) out[g * NC + f] = lg[f] - red;
}

extern "C" void kernel_launch(void* const* d_in, const int* in_sizes, int n_in,
                              void* d_out, int out_size, void* d_ws, size_t ws_size,
                              hipStream_t stream) {
    const float* x    = (const float*)d_in[0];
    const int*   ei   = (const int*)d_in[1];
    const int*   srcp = ei;
    const int*   dstp = ei + NE;
    const int*   batch = (const int*)d_in[2];
    const float* W[3]  = {(const float*)d_in[3],  (const float*)d_in[7],  (const float*)d_in[11]};
    const float* b[3]  = {(const float*)d_in[4],  (const float*)d_in[8],  (const float*)d_in[12]};
    const float* gm[3] = {(const float*)d_in[5],  (const float*)d_in[9],  (const float*)d_in[13]};
    const float* bt[3] = {(const float*)d_in[6],  (const float*)d_in[10], (const float*)d_in[14]};
    const float* w1 = (const float*)d_in[15];
    const float* b1 = (const float*)d_in[16];
    const float* w2 = (const float*)d_in[17];
    const float* b2 = (const float*)d_in[18];
    float* out = (float*)d_out;

    float* ws     = (float*)d_ws;
    float* dis    = ws;               // NN (deg, then dis in-place)
    float* A      = dis + NN;         // NN*H
    float* B      = A + (size_t)NN * H;  // NN*H
    float* sums   = B + (size_t)NN * H;  // 256 (colsum | colsumsq)
    float* ss     = sums + 256;       // 256 (scale | shift)
    float* pooled = ss + 256;         // NG*H
    float* counts = pooled + NG * H;  // NG

    hipMemsetAsync(dis, 0, NN * sizeof(float), stream);
    k_deg<<<(NE + 255) / 256, 256, 0, stream>>>(dstp, dis);
    k_dis<<<(NN + 255) / 256, 256, 0, stream>>>(dis);

    const float* xin = x;
    float* hbuf = A;
    float* aggbuf = B;
    for (int l = 0; l < 3; l++) {
        k_gemm<<<NN / 16, 256, 0, stream>>>(xin, W[l], hbuf);
        k_init_agg<<<NN * H / 256, 256, 0, stream>>>(hbuf, dis, b[l], aggbuf);
        k_scatter<<<NE / 2, 256, 0, stream>>>(hbuf, srcp, dstp, dis, aggbuf);
        hipMemsetAsync(sums, 0, 256 * sizeof(float), stream);
        k_stats<<<512, 128, 0, stream>>>(aggbuf, sums);
        k_scaleshift<<<1, 128, 0, stream>>>(sums, gm[l], bt[l], ss);
        k_bnrelu<<<NN * H / 256, 256, 0, stream>>>(aggbuf, ss, hbuf);  // BN out -> hbuf
        xin = hbuf;
        float* t = hbuf; hbuf = aggbuf; aggbuf = t;  // ping-pong
    }

    hipMemsetAsync(pooled, 0, (NG * H + NG) * sizeof(float), stream);
    k_pool<<<NN * H / 256, 256, 0, stream>>>(xin, batch, pooled, counts);
    k_head<<<NG, 128, 0, stream>>>(pooled, counts, w1, b1, w2, b2, out);
}

// Round 2
// 1350.029 us; speedup vs baseline: 2.6054x; 2.6054x over previous
//
#include <hip/hip_runtime.h>
#include <math.h>

constexpr int NN = 100000;   // nodes
constexpr int NE = 1600000;  // edges
constexpr int H  = 128;      // feat/hidden
constexpr int NG = 100;      // graphs
constexpr int NC = 10;       // classes

// ---------------- degree (int) ----------------
__global__ void k_deg(const int* __restrict__ dst, int* __restrict__ deg) {
    int e = blockIdx.x * 256 + threadIdx.x;
    if (e < NE) atomicAdd(&deg[dst[e]], 1);
}

__global__ void k_dis(const int* __restrict__ deg, float* __restrict__ dis) {
    int i = blockIdx.x * 256 + threadIdx.x;
    if (i < NN) dis[i] = rsqrtf((float)deg[i] + 1.0f);  // +1 self loop
}

// ---------------- exclusive scan of deg -> rowptr (3-kernel) ----------------
// chunk = 1024 elements per block, 256 threads x 4 elems
__global__ __launch_bounds__(256) void k_scan1(const int* __restrict__ deg, int* __restrict__ out,
                                               int* __restrict__ partials) {
    __shared__ int tsum[256];
    int base = blockIdx.x * 1024;
    int tid = threadIdx.x;
    int v[4]; int s = 0;
    #pragma unroll
    for (int k = 0; k < 4; k++) {
        int i = base + tid * 4 + k;
        v[k] = (i < NN) ? deg[i] : 0;
        s += v[k];
    }
    tsum[tid] = s;
    __syncthreads();
    for (int off = 1; off < 256; off <<= 1) {
        int t = (tid >= off) ? tsum[tid - off] : 0;
        __syncthreads();
        tsum[tid] += t;
        __syncthreads();
    }
    int run = (tid == 0) ? 0 : tsum[tid - 1];
    #pragma unroll
    for (int k = 0; k < 4; k++) {
        int i = base + tid * 4 + k;
        if (i < NN) out[i] = run;
        run += v[k];
    }
    if (tid == 255) partials[blockIdx.x] = tsum[255];
}

__global__ void k_scan2(int* __restrict__ partials, int nb) {
    __shared__ int s[128];
    int tid = threadIdx.x;
    s[tid] = (tid < nb) ? partials[tid] : 0;
    __syncthreads();
    if (tid == 0) { int run = 0; for (int i = 0; i < nb; i++) { int t = s[i]; s[i] = run; run += t; } }
    __syncthreads();
    if (tid < nb) partials[tid] = s[tid];
}

__global__ void k_scan3(int* __restrict__ rowptr, const int* __restrict__ partials,
                        int* __restrict__ cursor) {
    int i = blockIdx.x * 256 + threadIdx.x;
    if (i < NN) {
        int v = rowptr[i] + partials[i >> 10];
        rowptr[i] = v;
        cursor[i] = v;
    }
    if (i == 0) rowptr[NN] = NE;
}

// ---------------- CSR fill ----------------
__global__ void k_fill(const int* __restrict__ src, const int* __restrict__ dst,
                       int* __restrict__ cursor, int* __restrict__ col) {
    int e = blockIdx.x * 256 + threadIdx.x;
    if (e < NE) {
        int d = dst[e];
        int p = atomicAdd(&cursor[d], 1);
        col[p] = src[e];
    }
}

// ---------------- GEMM: Y[n,128] = X[n,128] @ W[128,128] ----------------
__global__ __launch_bounds__(256) void k_gemm(const float* __restrict__ X,
                                              const float* __restrict__ W,
                                              float* __restrict__ Y) {
    __shared__ __align__(16) float Ws[H][H];
    __shared__ __align__(16) float Xs[16][H + 4];
    int tid = threadIdx.x;
    for (int i = tid; i < H * H; i += 256) Ws[i >> 7][i & 127] = W[i];
    int row0 = blockIdx.x * 16;
    for (int i = tid; i < 16 * H; i += 256)
        Xs[i >> 7][i & 127] = X[(row0 + (i >> 7)) * H + (i & 127)];
    __syncthreads();

    int cx = tid & 31;
    int ry = tid >> 5;
    float a00 = 0.f, a01 = 0.f, a02 = 0.f, a03 = 0.f;
    float a10 = 0.f, a11 = 0.f, a12 = 0.f, a13 = 0.f;
    #pragma unroll 4
    for (int k = 0; k < H; k++) {
        float4 w = *(const float4*)&Ws[k][cx * 4];
        float x0 = Xs[ry * 2][k];
        float x1 = Xs[ry * 2 + 1][k];
        a00 += x0 * w.x; a01 += x0 * w.y; a02 += x0 * w.z; a03 += x0 * w.w;
        a10 += x1 * w.x; a11 += x1 * w.y; a12 += x1 * w.z; a13 += x1 * w.w;
    }
    *(float4*)&Y[(row0 + ry * 2 + 0) * H + cx * 4] = make_float4(a00, a01, a02, a03);
    *(float4*)&Y[(row0 + ry * 2 + 1) * H + cx * 4] = make_float4(a10, a11, a12, a13);
}

// ---------------- gather-side aggregate (fused self-loop + bias) ----------------
// out[d,:] = dis[d] * ( h[d,:]*dis[d] + sum_{s in N(d)} h[s,:]*dis[s] ) + bias
// 8 nodes per block (one wave-half of 32 lanes per node), float4 per lane.
__global__ __launch_bounds__(256) void k_agg(const float* __restrict__ h,
                                             const int* __restrict__ rowptr,
                                             const int* __restrict__ col,
                                             const float* __restrict__ dis,
                                             const float* __restrict__ bias,
                                             float* __restrict__ out) {
    int node = blockIdx.x * 8 + (threadIdx.x >> 5);
    int lane = threadIdx.x & 31;
    int beg = rowptr[node], end = rowptr[node + 1];
    float dd = dis[node];
    const float4* h4 = (const float4*)h;
    float4 a = h4[(size_t)node * 32 + lane];
    float4 acc = make_float4(a.x * dd, a.y * dd, a.z * dd, a.w * dd);
    for (int j = beg; j < end; j++) {
        int s = col[j];
        float ds = dis[s];
        float4 v = h4[(size_t)s * 32 + lane];
        acc.x += v.x * ds; acc.y += v.y * ds; acc.z += v.z * ds; acc.w += v.w * ds;
    }
    float4 bb = ((const float4*)bias)[lane];
    ((float4*)out)[(size_t)node * 32 + lane] =
        make_float4(acc.x * dd + bb.x, acc.y * dd + bb.y, acc.z * dd + bb.z, acc.w * dd + bb.w);
}

// ---------------- BN column stats ----------------
__global__ void k_stats(const float* __restrict__ x, float* __restrict__ sums) {
    int f = threadIdx.x;  // 128 threads
    float s = 0.f, s2 = 0.f;
    for (int r = blockIdx.x; r < NN; r += gridDim.x) {
        float v = x[r * H + f];
        s += v; s2 += v * v;
    }
    atomicAdd(&sums[f], s);
    atomicAdd(&sums[128 + f], s2);
}

__global__ void k_scaleshift(const float* __restrict__ sums, const float* __restrict__ gamma,
                             const float* __restrict__ beta, float* __restrict__ ss) {
    int f = threadIdx.x;
    float mean = sums[f] * (1.0f / NN);
    float var  = sums[128 + f] * (1.0f / NN) - mean * mean;
    float sc   = gamma[f] * rsqrtf(var + 1e-5f);
    ss[f] = sc;
    ss[128 + f] = beta[f] - mean * sc;
}

__global__ void k_bnrelu(const float* __restrict__ agg, const float* __restrict__ ss,
                         float* __restrict__ out) {
    int idx = blockIdx.x * 256 + threadIdx.x;
    int f = idx & 127;
    float v = agg[idx] * ss[f] + ss[128 + f];
    out[idx] = v > 0.f ? v : 0.f;
}

// ---------------- graph segment boundaries (batch is sorted) ----------------
__global__ void k_gstart(const int* __restrict__ batch, int* __restrict__ gstart) {
    int g = threadIdx.x;  // 128 threads, need 0..NG
    if (g > NG) return;
    if (g == NG) { gstart[g] = NN; return; }
    int lo = 0, hi = NN;
    while (lo < hi) { int mid = (lo + hi) >> 1; if (batch[mid] < g) lo = mid + 1; else hi = mid; }
    gstart[g] = lo;
}

// ---------------- mean pool, no atomics: one block per graph ----------------
__global__ __launch_bounds__(256) void k_pool2(const float* __restrict__ x,
                                               const int* __restrict__ gstart,
                                               float* __restrict__ pooled) {
    int g = blockIdx.x;
    int beg = gstart[g], end = gstart[g + 1];
    int lane = threadIdx.x & 31;   // float4 column
    int walker = threadIdx.x >> 5; // 8 row walkers
    const float4* x4 = (const float4*)x;
    float4 acc = make_float4(0.f, 0.f, 0.f, 0.f);
    for (int r = beg + walker; r < end; r += 8) {
        float4 v = x4[(size_t)r * 32 + lane];
        acc.x += v.x; acc.y += v.y; acc.z += v.z; acc.w += v.w;
    }
    __shared__ float4 red[256];
    red[threadIdx.x] = acc;
    __syncthreads();
    if (threadIdx.x < 32) {
        float4 s = red[threadIdx.x];
        for (int w = 1; w < 8; w++) {
            float4 v = red[w * 32 + threadIdx.x];
            s.x += v.x; s.y += v.y; s.z += v.z; s.w += v.w;
        }
        float inv = 1.0f / fmaxf((float)(end - beg), 1.0f);
        ((float4*)pooled)[g * 32 + threadIdx.x] =
            make_float4(s.x * inv, s.y * inv, s.z * inv, s.w * inv);
    }
}

// ---------------- MLP head + log_softmax ----------------
__global__ __launch_bounds__(128) void k_head(const float* __restrict__ pooled,
                                              const float* __restrict__ w1, const float* __restrict__ b1,
                                              const float* __restrict__ w2, const float* __restrict__ b2,
                                              float* __restrict__ out) {
    __shared__ float p[H], hh[H], lg[NC], red;
    int g = blockIdx.x, f = threadIdx.x;
    p[f] = pooled[g * H + f];
    __syncthreads();
    float a = b1[f];
    for (int k = 0; k < H; k++) a += p[k] * w1[k * H + f];
    hh[f] = a > 0.f ? a : 0.f;
    __syncthreads();
    if (f < NC) {
        float l = b2[f];
        for (int k = 0; k < H; k++) l += hh[k] * w2[k * NC + f];
        lg[f] = l;
    }
    __syncthreads();
    if (f == 0) {
        float m = lg[0];
        for (int c = 1; c < NC; c++) m = m > lg[c] ? m : lg[c];
        float s = 0.f;
        for (int c = 0; c < NC; c++) s += expf(lg[c] - m);
        red = m + logf(s);
    }
    __syncthreads();
    if (f < NC) out[g * NC + f] = lg[f] - red;
}

extern "C" void kernel_launch(void* const* d_in, const int* in_sizes, int n_in,
                              void* d_out, int out_size, void* d_ws, size_t ws_size,
                              hipStream_t stream) {
    const float* x     = (const float*)d_in[0];
    const int*   ei    = (const int*)d_in[1];
    const int*   srcp  = ei;
    const int*   dstp  = ei + NE;
    const int*   batch = (const int*)d_in[2];
    const float* W[3]  = {(const float*)d_in[3],  (const float*)d_in[7],  (const float*)d_in[11]};
    const float* b[3]  = {(const float*)d_in[4],  (const float*)d_in[8],  (const float*)d_in[12]};
    const float* gm[3] = {(const float*)d_in[5],  (const float*)d_in[9],  (const float*)d_in[13]};
    const float* bt[3] = {(const float*)d_in[6],  (const float*)d_in[10], (const float*)d_in[14]};
    const float* w1 = (const float*)d_in[15];
    const float* b1 = (const float*)d_in[16];
    const float* w2 = (const float*)d_in[17];
    const float* b2 = (const float*)d_in[18];
    float* out = (float*)d_out;

    // workspace layout (element offsets in 4-byte units; all float4 users 16B-aligned)
    float* ws   = (float*)d_ws;
    float* dis     = ws;                         // [0, 100000)
    int*   deg_i   = (int*)(ws + 100000);        // doubles as cursor after scan
    int*   rowptr  = (int*)(ws + 200000);        // NN+1, padded region 100004
    int*   partials= (int*)(ws + 300004);        // 128
    int*   gstart  = (int*)(ws + 300132);        // 104
    float* sums    = ws + 300236;                // 256
    float* ss      = ws + 300492;                // 256
    float* pooled  = ws + 300748;                // 12800
    int*   col     = (int*)(ws + 313548);        // NE
    float* A       = ws + 1913548;               // NN*H
    float* B       = ws + 14713548;              // NN*H

    const int nScanBlocks = (NN + 1023) / 1024;  // 98

    hipMemsetAsync(deg_i, 0, NN * sizeof(int), stream);
    k_deg<<<(NE + 255) / 256, 256, 0, stream>>>(dstp, deg_i);
    k_dis<<<(NN + 255) / 256, 256, 0, stream>>>(deg_i, dis);
    k_scan1<<<nScanBlocks, 256, 0, stream>>>(deg_i, rowptr, partials);
    k_scan2<<<1, 128, 0, stream>>>(partials, nScanBlocks);
    k_scan3<<<(NN + 255) / 256, 256, 0, stream>>>(rowptr, partials, deg_i /*cursor*/);
    k_fill<<<(NE + 255) / 256, 256, 0, stream>>>(srcp, dstp, deg_i, col);
    k_gstart<<<1, 128, 0, stream>>>(batch, gstart);

    const float* xin = x;
    float* hbuf = A;
    float* aggbuf = B;
    for (int l = 0; l < 3; l++) {
        k_gemm<<<NN / 16, 256, 0, stream>>>(xin, W[l], hbuf);
        k_agg<<<NN / 8, 256, 0, stream>>>(hbuf, rowptr, col, dis, b[l], aggbuf);
        hipMemsetAsync(sums, 0, 256 * sizeof(float), stream);
        k_stats<<<512, 128, 0, stream>>>(aggbuf, sums);
        k_scaleshift<<<1, 128, 0, stream>>>(sums, gm[l], bt[l], ss);
        k_bnrelu<<<NN * H / 256, 256, 0, stream>>>(aggbuf, ss, hbuf);
        xin = hbuf;
        float* t = hbuf; hbuf = aggbuf; aggbuf = t;
    }

    k_pool2<<<NG, 256, 0, stream>>>(xin, gstart, pooled);
    k_head<<<NG, 128, 0, stream>>>(pooled, w1, b1, w2, b2, out);
}

// Round 3
// 1199.261 us; speedup vs baseline: 2.9330x; 1.1257x over previous
//
#include <hip/hip_runtime.h>
#include <hip/hip_bf16.h>
#include <math.h>

constexpr int NN = 100000;   // nodes
constexpr int NE = 1600000;  // edges
constexpr int H  = 128;      // feat/hidden
constexpr int NG = 100;      // graphs
constexpr int NC = 10;       // classes

static __device__ __forceinline__ float bf2f(unsigned short s) {
    unsigned int u = ((unsigned int)s) << 16;
    float f;
    __builtin_memcpy(&f, &u, 4);
    return f;
}

static __device__ __forceinline__ unsigned short f2bf(float f) {
    __hip_bfloat16 b = __float2bfloat16(f);  // RNE
    return *(unsigned short*)&b;
}

// ---------------- degree (int) ----------------
__global__ void k_deg(const int* __restrict__ dst, int* __restrict__ deg) {
    int e = blockIdx.x * 256 + threadIdx.x;
    if (e < NE) atomicAdd(&deg[dst[e]], 1);
}

__global__ void k_dis(const int* __restrict__ deg, float* __restrict__ dis) {
    int i = blockIdx.x * 256 + threadIdx.x;
    if (i < NN) dis[i] = rsqrtf((float)deg[i] + 1.0f);  // +1 self loop
}

// ---------------- exclusive scan of deg -> rowptr ----------------
__global__ __launch_bounds__(256) void k_scan1(const int* __restrict__ deg, int* __restrict__ out,
                                               int* __restrict__ partials) {
    __shared__ int tsum[256];
    int base = blockIdx.x * 1024;
    int tid = threadIdx.x;
    int v[4]; int s = 0;
    #pragma unroll
    for (int k = 0; k < 4; k++) {
        int i = base + tid * 4 + k;
        v[k] = (i < NN) ? deg[i] : 0;
        s += v[k];
    }
    tsum[tid] = s;
    __syncthreads();
    for (int off = 1; off < 256; off <<= 1) {
        int t = (tid >= off) ? tsum[tid - off] : 0;
        __syncthreads();
        tsum[tid] += t;
        __syncthreads();
    }
    int run = (tid == 0) ? 0 : tsum[tid - 1];
    #pragma unroll
    for (int k = 0; k < 4; k++) {
        int i = base + tid * 4 + k;
        if (i < NN) out[i] = run;
        run += v[k];
    }
    if (tid == 255) partials[blockIdx.x] = tsum[255];
}

__global__ void k_scan2(int* __restrict__ partials, int nb) {
    __shared__ int s[128];
    int tid = threadIdx.x;
    s[tid] = (tid < nb) ? partials[tid] : 0;
    __syncthreads();
    if (tid == 0) { int run = 0; for (int i = 0; i < nb; i++) { int t = s[i]; s[i] = run; run += t; } }
    __syncthreads();
    if (tid < nb) partials[tid] = s[tid];
}

__global__ void k_scan3(int* __restrict__ rowptr, const int* __restrict__ partials,
                        int* __restrict__ cursor) {
    int i = blockIdx.x * 256 + threadIdx.x;
    if (i < NN) {
        int v = rowptr[i] + partials[i >> 10];
        rowptr[i] = v;
        cursor[i] = v;
    }
    if (i == 0) rowptr[NN] = NE;
}

// ---------------- CSR fill ----------------
__global__ void k_fill(const int* __restrict__ src, const int* __restrict__ dst,
                       int* __restrict__ cursor, int* __restrict__ col) {
    int e = blockIdx.x * 256 + threadIdx.x;
    if (e < NE) {
        int d = dst[e];
        int p = atomicAdd(&cursor[d], 1);
        col[p] = src[e];
    }
}

// ---------------- fused GEMM: Y_bf16 = relu?(X*scale+shift) @ W ----------------
// ss == nullptr -> identity staging (layer 0). relu applied only when ss != nullptr.
__global__ __launch_bounds__(256) void k_gemm(const float* __restrict__ X,
                                              const float* __restrict__ ss, int relu,
                                              const float* __restrict__ W,
                                              unsigned short* __restrict__ Y) {
    __shared__ __align__(16) float Ws[H][H];
    __shared__ __align__(16) float Xs[16][H + 4];
    int tid = threadIdx.x;
    for (int i = tid; i < H * H; i += 256) Ws[i >> 7][i & 127] = W[i];
    int row0 = blockIdx.x * 16;
    for (int i = tid; i < 16 * H; i += 256) {
        int f = i & 127;
        float v = X[(size_t)(row0 + (i >> 7)) * H + f];
        if (ss) {
            v = v * ss[f] + ss[128 + f];
            if (relu) v = fmaxf(v, 0.f);
        }
        Xs[i >> 7][f] = v;
    }
    __syncthreads();

    int cx = tid & 31;
    int ry = tid >> 5;
    float a00 = 0.f, a01 = 0.f, a02 = 0.f, a03 = 0.f;
    float a10 = 0.f, a11 = 0.f, a12 = 0.f, a13 = 0.f;
    #pragma unroll 4
    for (int k = 0; k < H; k++) {
        float4 w = *(const float4*)&Ws[k][cx * 4];
        float x0 = Xs[ry * 2][k];
        float x1 = Xs[ry * 2 + 1][k];
        a00 += x0 * w.x; a01 += x0 * w.y; a02 += x0 * w.z; a03 += x0 * w.w;
        a10 += x1 * w.x; a11 += x1 * w.y; a12 += x1 * w.z; a13 += x1 * w.w;
    }
    ushort4* Y4 = (ushort4*)Y;
    Y4[(size_t)(row0 + ry * 2 + 0) * 32 + cx] =
        make_ushort4(f2bf(a00), f2bf(a01), f2bf(a02), f2bf(a03));
    Y4[(size_t)(row0 + ry * 2 + 1) * 32 + cx] =
        make_ushort4(f2bf(a10), f2bf(a11), f2bf(a12), f2bf(a13));
}

// ---------------- gather-side aggregate (bf16 h, fused self-loop + bias) ----------------
// out[d,:] = dis[d] * ( h[d,:]*dis[d] + sum_{s in N(d)} h[s,:]*dis[s] ) + bias
__global__ __launch_bounds__(256) void k_agg(const unsigned short* __restrict__ h,
                                             const int* __restrict__ rowptr,
                                             const int* __restrict__ col,
                                             const float* __restrict__ dis,
                                             const float* __restrict__ bias,
                                             float* __restrict__ out) {
    int node = blockIdx.x * 8 + (threadIdx.x >> 5);
    int lane = threadIdx.x & 31;
    int beg = rowptr[node], end = rowptr[node + 1];
    float dd = dis[node];
    const ushort4* h4 = (const ushort4*)h;
    ushort4 a = h4[(size_t)node * 32 + lane];
    float4 acc = make_float4(bf2f(a.x) * dd, bf2f(a.y) * dd, bf2f(a.z) * dd, bf2f(a.w) * dd);
    for (int j = beg; j < end; j++) {
        int s = col[j];
        float ds = dis[s];
        ushort4 v = h4[(size_t)s * 32 + lane];
        acc.x += bf2f(v.x) * ds; acc.y += bf2f(v.y) * ds;
        acc.z += bf2f(v.z) * ds; acc.w += bf2f(v.w) * ds;
    }
    float4 bb = ((const float4*)bias)[lane];
    ((float4*)out)[(size_t)node * 32 + lane] =
        make_float4(acc.x * dd + bb.x, acc.y * dd + bb.y, acc.z * dd + bb.z, acc.w * dd + bb.w);
}

// ---------------- BN column stats ----------------
__global__ void k_stats(const float* __restrict__ x, float* __restrict__ sums) {
    int f = threadIdx.x;  // 128 threads
    float s = 0.f, s2 = 0.f;
    for (int r = blockIdx.x; r < NN; r += gridDim.x) {
        float v = x[r * H + f];
        s += v; s2 += v * v;
    }
    atomicAdd(&sums[f], s);
    atomicAdd(&sums[128 + f], s2);
}

__global__ void k_scaleshift(const float* __restrict__ sums, const float* __restrict__ gamma,
                             const float* __restrict__ beta, float* __restrict__ ss) {
    int f = threadIdx.x;
    float mean = sums[f] * (1.0f / NN);
    float var  = sums[128 + f] * (1.0f / NN) - mean * mean;
    float sc   = gamma[f] * rsqrtf(var + 1e-5f);
    ss[f] = sc;
    ss[128 + f] = beta[f] - mean * sc;
}

// ---------------- graph segment boundaries (batch is sorted) ----------------
__global__ void k_gstart(const int* __restrict__ batch, int* __restrict__ gstart) {
    int g = threadIdx.x;
    if (g > NG) return;
    if (g == NG) { gstart[g] = NN; return; }
    int lo = 0, hi = NN;
    while (lo < hi) { int mid = (lo + hi) >> 1; if (batch[mid] < g) lo = mid + 1; else hi = mid; }
    gstart[g] = lo;
}

// ---------------- mean pool with fused BN+ReLU; one block per graph ----------------
__global__ __launch_bounds__(256) void k_pool2(const float* __restrict__ x,
                                               const float* __restrict__ ss,
                                               const int* __restrict__ gstart,
                                               float* __restrict__ pooled) {
    int g = blockIdx.x;
    int beg = gstart[g], end = gstart[g + 1];
    int lane = threadIdx.x & 31;   // float4 column
    int walker = threadIdx.x >> 5; // 8 row walkers
    const float4* x4 = (const float4*)x;
    float4 sc = ((const float4*)ss)[lane];
    float4 sh = ((const float4*)(ss + 128))[lane];
    float4 acc = make_float4(0.f, 0.f, 0.f, 0.f);
    for (int r = beg + walker; r < end; r += 8) {
        float4 v = x4[(size_t)r * 32 + lane];
        acc.x += fmaxf(v.x * sc.x + sh.x, 0.f);
        acc.y += fmaxf(v.y * sc.y + sh.y, 0.f);
        acc.z += fmaxf(v.z * sc.z + sh.z, 0.f);
        acc.w += fmaxf(v.w * sc.w + sh.w, 0.f);
    }
    __shared__ float4 red[256];
    red[threadIdx.x] = acc;
    __syncthreads();
    if (threadIdx.x < 32) {
        float4 s = red[threadIdx.x];
        for (int w = 1; w < 8; w++) {
            float4 v = red[w * 32 + threadIdx.x];
            s.x += v.x; s.y += v.y; s.z += v.z; s.w += v.w;
        }
        float inv = 1.0f / fmaxf((float)(end - beg), 1.0f);
        ((float4*)pooled)[g * 32 + threadIdx.x] =
            make_float4(s.x * inv, s.y * inv, s.z * inv, s.w * inv);
    }
}

// ---------------- MLP head + log_softmax ----------------
__global__ __launch_bounds__(128) void k_head(const float* __restrict__ pooled,
                                              const float* __restrict__ w1, const float* __restrict__ b1,
                                              const float* __restrict__ w2, const float* __restrict__ b2,
                                              float* __restrict__ out) {
    __shared__ float p[H], hh[H], lg[NC], red;
    int g = blockIdx.x, f = threadIdx.x;
    p[f] = pooled[g * H + f];
    __syncthreads();
    float a = b1[f];
    for (int k = 0; k < H; k++) a += p[k] * w1[k * H + f];
    hh[f] = a > 0.f ? a : 0.f;
    __syncthreads();
    if (f < NC) {
        float l = b2[f];
        for (int k = 0; k < H; k++) l += hh[k] * w2[k * NC + f];
        lg[f] = l;
    }
    __syncthreads();
    if (f == 0) {
        float m = lg[0];
        for (int c = 1; c < NC; c++) m = m > lg[c] ? m : lg[c];
        float s = 0.f;
        for (int c = 0; c < NC; c++) s += expf(lg[c] - m);
        red = m + logf(s);
    }
    __syncthreads();
    if (f < NC) out[g * NC + f] = lg[f] - red;
}

extern "C" void kernel_launch(void* const* d_in, const int* in_sizes, int n_in,
                              void* d_out, int out_size, void* d_ws, size_t ws_size,
                              hipStream_t stream) {
    const float* x     = (const float*)d_in[0];
    const int*   ei    = (const int*)d_in[1];
    const int*   srcp  = ei;
    const int*   dstp  = ei + NE;
    const int*   batch = (const int*)d_in[2];
    const float* W[3]  = {(const float*)d_in[3],  (const float*)d_in[7],  (const float*)d_in[11]};
    const float* b[3]  = {(const float*)d_in[4],  (const float*)d_in[8],  (const float*)d_in[12]};
    const float* gm[3] = {(const float*)d_in[5],  (const float*)d_in[9],  (const float*)d_in[13]};
    const float* bt[3] = {(const float*)d_in[6],  (const float*)d_in[10], (const float*)d_in[14]};
    const float* w1 = (const float*)d_in[15];
    const float* b1 = (const float*)d_in[16];
    const float* w2 = (const float*)d_in[17];
    const float* b2 = (const float*)d_in[18];
    float* out = (float*)d_out;

    // workspace layout (offsets in floats; float4 users at 16B-aligned offsets)
    float* ws       = (float*)d_ws;
    float* dis      = ws;                          // 100000
    int*   deg_i    = (int*)(ws + 100000);         // 100000 (doubles as cursor)
    int*   rowptr   = (int*)(ws + 200000);         // 100004
    int*   partials = (int*)(ws + 300004);         // 128
    int*   gstart   = (int*)(ws + 300132);         // 104
    float* sums     = ws + 300236;                 // 256
    float* ssbuf    = ws + 300492;                 // 3 * 256
    float* pooled   = ws + 301260;                 // 12800
    int*   col      = (int*)(ws + 314060);         // NE
    float* aggbuf   = ws + 1914060;                // NN*H f32
    unsigned short* hb = (unsigned short*)(ws + 14714060);  // NN*H bf16

    const int nScanBlocks = (NN + 1023) / 1024;  // 98

    hipMemsetAsync(deg_i, 0, NN * sizeof(int), stream);
    k_deg<<<(NE + 255) / 256, 256, 0, stream>>>(dstp, deg_i);
    k_dis<<<(NN + 255) / 256, 256, 0, stream>>>(deg_i, dis);
    k_scan1<<<nScanBlocks, 256, 0, stream>>>(deg_i, rowptr, partials);
    k_scan2<<<1, 128, 0, stream>>>(partials, nScanBlocks);
    k_scan3<<<(NN + 255) / 256, 256, 0, stream>>>(rowptr, partials, deg_i /*cursor*/);
    k_fill<<<(NE + 255) / 256, 256, 0, stream>>>(srcp, dstp, deg_i, col);
    k_gstart<<<1, 128, 0, stream>>>(batch, gstart);

    const float* xin = x;
    const float* ss_prev = nullptr;
    for (int l = 0; l < 3; l++) {
        float* ss = ssbuf + l * 256;
        k_gemm<<<NN / 16, 256, 0, stream>>>(xin, ss_prev, 1, W[l], hb);
        k_agg<<<NN / 8, 256, 0, stream>>>(hb, rowptr, col, dis, b[l], aggbuf);
        hipMemsetAsync(sums, 0, 256 * sizeof(float), stream);
        k_stats<<<1024, 128, 0, stream>>>(aggbuf, sums);
        k_scaleshift<<<1, 128, 0, stream>>>(sums, gm[l], bt[l], ss);
        xin = aggbuf;       // next gemm reads agg with ss applied in staging
        ss_prev = ss;
    }

    k_pool2<<<NG, 256, 0, stream>>>(aggbuf, ssbuf + 2 * 256, gstart, pooled);
    k_head<<<NG, 128, 0, stream>>>(pooled, w1, b1, w2, b2, out);
}

// Round 4
// 945.717 us; speedup vs baseline: 3.7193x; 1.2681x over previous
//
#include <hip/hip_runtime.h>
#include <math.h>

constexpr int NN = 100000;   // nodes
constexpr int NE = 1600000;  // edges
constexpr int H  = 128;      // feat/hidden
constexpr int NG = 100;      // graphs
constexpr int NC = 10;       // classes

typedef _Float16 half8 __attribute__((ext_vector_type(8)));
typedef _Float16 half4 __attribute__((ext_vector_type(4)));
typedef float    f32x4 __attribute__((ext_vector_type(4)));

// ---------------- degree (int) ----------------
__global__ void k_deg(const int* __restrict__ dst, int* __restrict__ deg) {
    int e = blockIdx.x * 256 + threadIdx.x;
    if (e < NE) atomicAdd(&deg[dst[e]], 1);
}

__global__ void k_dis(const int* __restrict__ deg, float* __restrict__ dis) {
    int i = blockIdx.x * 256 + threadIdx.x;
    if (i < NN) dis[i] = rsqrtf((float)deg[i] + 1.0f);  // +1 self loop
}

// ---------------- exclusive scan of deg -> rowptr ----------------
__global__ __launch_bounds__(256) void k_scan1(const int* __restrict__ deg, int* __restrict__ out,
                                               int* __restrict__ partials) {
    __shared__ int tsum[256];
    int base = blockIdx.x * 1024;
    int tid = threadIdx.x;
    int v[4]; int s = 0;
    #pragma unroll
    for (int k = 0; k < 4; k++) {
        int i = base + tid * 4 + k;
        v[k] = (i < NN) ? deg[i] : 0;
        s += v[k];
    }
    tsum[tid] = s;
    __syncthreads();
    for (int off = 1; off < 256; off <<= 1) {
        int t = (tid >= off) ? tsum[tid - off] : 0;
        __syncthreads();
        tsum[tid] += t;
        __syncthreads();
    }
    int run = (tid == 0) ? 0 : tsum[tid - 1];
    #pragma unroll
    for (int k = 0; k < 4; k++) {
        int i = base + tid * 4 + k;
        if (i < NN) out[i] = run;
        run += v[k];
    }
    if (tid == 255) partials[blockIdx.x] = tsum[255];
}

__global__ void k_scan2(int* __restrict__ partials, int nb) {
    __shared__ int s[128];
    int tid = threadIdx.x;
    s[tid] = (tid < nb) ? partials[tid] : 0;
    __syncthreads();
    if (tid == 0) { int run = 0; for (int i = 0; i < nb; i++) { int t = s[i]; s[i] = run; run += t; } }
    __syncthreads();
    if (tid < nb) partials[tid] = s[tid];
}

__global__ void k_scan3(int* __restrict__ rowptr, const int* __restrict__ partials,
                        int* __restrict__ cursor) {
    int i = blockIdx.x * 256 + threadIdx.x;
    if (i < NN) {
        int v = rowptr[i] + partials[i >> 10];
        rowptr[i] = v;
        cursor[i] = v;
    }
    if (i == 0) rowptr[NN] = NE;
}

// ---------------- CSR fill ----------------
__global__ void k_fill(const int* __restrict__ src, const int* __restrict__ dst,
                       int* __restrict__ cursor, int* __restrict__ col) {
    int e = blockIdx.x * 256 + threadIdx.x;
    if (e < NE) {
        int d = dst[e];
        int p = atomicAdd(&cursor[d], 1);
        col[p] = src[e];
    }
}

// ---------------- W -> Wt (transposed, f16) once per layer ----------------
__global__ void k_prepw(const float* __restrict__ W, _Float16* __restrict__ Wt) {
    int idx = blockIdx.x * 256 + threadIdx.x;  // 16384
    int n = idx >> 7, k = idx & 127;
    Wt[idx] = (_Float16)W[k * 128 + n];
}

// ---------------- MFMA GEMM: Y_f16 = relu?(X*scale+shift) @ W ----------------
// 64 rows x 128 cols per block; 4 waves, each wave 16 rows x all 128 cols.
// A layout: A[m=lane&15][k=quad*8+j]; B staged as Wt[n][k] so both are 16B ds_read.
// C/D: col=lane&15, row=quad*4+reg  (m89-verified).
__global__ __launch_bounds__(256) void k_gemm(const float* __restrict__ X,
                                              const float* __restrict__ ss,
                                              const _Float16* __restrict__ Wt,
                                              _Float16* __restrict__ Y) {
    __shared__ _Float16 Wl[128][136];  // +8 pad: row stride 272B keeps 16B align, breaks bank pattern
    __shared__ _Float16 Xl[64][136];
    int tid = threadIdx.x;
    int row0 = blockIdx.x * 64;

    // stage Wt (16384 halves, 16B chunks)
    #pragma unroll
    for (int p = 0; p < 8; p++) {
        int idx = p * 2048 + tid * 8;
        int r = idx >> 7, c = idx & 127;
        *(uint4*)&Wl[r][c] = ((const uint4*)Wt)[idx >> 3];
    }
    // stage X tile with fused BN+ReLU, f32 -> f16
    #pragma unroll
    for (int p = 0; p < 8; p++) {
        int idx = p * 1024 + tid * 4;
        int r = idx >> 7, c = idx & 127;
        int gr = row0 + r;
        float4 v = make_float4(0.f, 0.f, 0.f, 0.f);
        if (gr < NN) v = *(const float4*)&X[(size_t)gr * H + c];
        if (ss) {
            float4 sc = ((const float4*)ss)[c >> 2];
            float4 sh = ((const float4*)(ss + 128))[c >> 2];
            v.x = fmaxf(v.x * sc.x + sh.x, 0.f);
            v.y = fmaxf(v.y * sc.y + sh.y, 0.f);
            v.z = fmaxf(v.z * sc.z + sh.z, 0.f);
            v.w = fmaxf(v.w * sc.w + sh.w, 0.f);
        }
        half4 hv = {(_Float16)v.x, (_Float16)v.y, (_Float16)v.z, (_Float16)v.w};
        *(half4*)&Xl[r][c] = hv;
    }
    __syncthreads();

    int wave = tid >> 6;
    int lane = tid & 63;
    int m = lane & 15;
    int quad = lane >> 4;

    half8 afrag[4];
    #pragma unroll
    for (int kc = 0; kc < 4; kc++)
        afrag[kc] = *(const half8*)&Xl[wave * 16 + m][kc * 32 + quad * 8];

    f32x4 acc[8];
    #pragma unroll
    for (int nt = 0; nt < 8; nt++) acc[nt] = (f32x4){0.f, 0.f, 0.f, 0.f};

    #pragma unroll
    for (int kc = 0; kc < 4; kc++) {
        #pragma unroll
        for (int nt = 0; nt < 8; nt++) {
            half8 b = *(const half8*)&Wl[nt * 16 + m][kc * 32 + quad * 8];
            acc[nt] = __builtin_amdgcn_mfma_f32_16x16x32_f16(afrag[kc], b, acc[nt], 0, 0, 0);
        }
    }

    #pragma unroll
    for (int nt = 0; nt < 8; nt++) {
        int c = nt * 16 + m;
        #pragma unroll
        for (int r = 0; r < 4; r++) {
            int gr = row0 + wave * 16 + quad * 4 + r;
            if (gr < NN) Y[(size_t)gr * H + c] = (_Float16)acc[nt][r];
        }
    }
}

// ---------------- gather-side aggregate (f16 h, fused self-loop + bias) ----------------
__global__ __launch_bounds__(256) void k_agg(const _Float16* __restrict__ h,
                                             const int* __restrict__ rowptr,
                                             const int* __restrict__ col,
                                             const float* __restrict__ dis,
                                             const float* __restrict__ bias,
                                             float* __restrict__ out) {
    int node = blockIdx.x * 8 + (threadIdx.x >> 5);
    int lane = threadIdx.x & 31;
    int beg = rowptr[node], end = rowptr[node + 1];
    float dd = dis[node];
    const half4* h4 = (const half4*)h;
    half4 a = h4[(size_t)node * 32 + lane];
    float4 acc = make_float4((float)a.x * dd, (float)a.y * dd, (float)a.z * dd, (float)a.w * dd);
    for (int j = beg; j < end; j++) {
        int s = col[j];
        float ds = dis[s];
        half4 v = h4[(size_t)s * 32 + lane];
        acc.x += (float)v.x * ds; acc.y += (float)v.y * ds;
        acc.z += (float)v.z * ds; acc.w += (float)v.w * ds;
    }
    float4 bb = ((const float4*)bias)[lane];
    ((float4*)out)[(size_t)node * 32 + lane] =
        make_float4(acc.x * dd + bb.x, acc.y * dd + bb.y, acc.z * dd + bb.z, acc.w * dd + bb.w);
}

// ---------------- BN column stats ----------------
__global__ void k_stats(const float* __restrict__ x, float* __restrict__ sums) {
    int f = threadIdx.x;  // 128 threads
    float s = 0.f, s2 = 0.f;
    for (int r = blockIdx.x; r < NN; r += gridDim.x) {
        float v = x[r * H + f];
        s += v; s2 += v * v;
    }
    atomicAdd(&sums[f], s);
    atomicAdd(&sums[128 + f], s2);
}

__global__ void k_scaleshift(const float* __restrict__ sums, const float* __restrict__ gamma,
                             const float* __restrict__ beta, float* __restrict__ ss) {
    int f = threadIdx.x;
    float mean = sums[f] * (1.0f / NN);
    float var  = sums[128 + f] * (1.0f / NN) - mean * mean;
    float sc   = gamma[f] * rsqrtf(var + 1e-5f);
    ss[f] = sc;
    ss[128 + f] = beta[f] - mean * sc;
}

// ---------------- graph segment boundaries (batch is sorted) ----------------
__global__ void k_gstart(const int* __restrict__ batch, int* __restrict__ gstart) {
    int g = threadIdx.x;
    if (g > NG) return;
    if (g == NG) { gstart[g] = NN; return; }
    int lo = 0, hi = NN;
    while (lo < hi) { int mid = (lo + hi) >> 1; if (batch[mid] < g) lo = mid + 1; else hi = mid; }
    gstart[g] = lo;
}

// ---------------- mean pool with fused BN+ReLU; one block per graph ----------------
__global__ __launch_bounds__(256) void k_pool2(const float* __restrict__ x,
                                               const float* __restrict__ ss,
                                               const int* __restrict__ gstart,
                                               float* __restrict__ pooled) {
    int g = blockIdx.x;
    int beg = gstart[g], end = gstart[g + 1];
    int lane = threadIdx.x & 31;
    int walker = threadIdx.x >> 5;
    const float4* x4 = (const float4*)x;
    float4 sc = ((const float4*)ss)[lane];
    float4 sh = ((const float4*)(ss + 128))[lane];
    float4 acc = make_float4(0.f, 0.f, 0.f, 0.f);
    for (int r = beg + walker; r < end; r += 8) {
        float4 v = x4[(size_t)r * 32 + lane];
        acc.x += fmaxf(v.x * sc.x + sh.x, 0.f);
        acc.y += fmaxf(v.y * sc.y + sh.y, 0.f);
        acc.z += fmaxf(v.z * sc.z + sh.z, 0.f);
        acc.w += fmaxf(v.w * sc.w + sh.w, 0.f);
    }
    __shared__ float4 red[256];
    red[threadIdx.x] = acc;
    __syncthreads();
    if (threadIdx.x < 32) {
        float4 s = red[threadIdx.x];
        for (int w = 1; w < 8; w++) {
            float4 v = red[w * 32 + threadIdx.x];
            s.x += v.x; s.y += v.y; s.z += v.z; s.w += v.w;
        }
        float inv = 1.0f / fmaxf((float)(end - beg), 1.0f);
        ((float4*)pooled)[g * 32 + threadIdx.x] =
            make_float4(s.x * inv, s.y * inv, s.z * inv, s.w * inv);
    }
}

// ---------------- MLP head + log_softmax ----------------
__global__ __launch_bounds__(128) void k_head(const float* __restrict__ pooled,
                                              const float* __restrict__ w1, const float* __restrict__ b1,
                                              const float* __restrict__ w2, const float* __restrict__ b2,
                                              float* __restrict__ out) {
    __shared__ float p[H], hh[H], lg[NC], red;
    int g = blockIdx.x, f = threadIdx.x;
    p[f] = pooled[g * H + f];
    __syncthreads();
    float a = b1[f];
    for (int k = 0; k < H; k++) a += p[k] * w1[k * H + f];
    hh[f] = a > 0.f ? a : 0.f;
    __syncthreads();
    if (f < NC) {
        float l = b2[f];
        for (int k = 0; k < H; k++) l += hh[k] * w2[k * NC + f];
        lg[f] = l;
    }
    __syncthreads();
    if (f == 0) {
        float m = lg[0];
        for (int c = 1; c < NC; c++) m = m > lg[c] ? m : lg[c];
        float s = 0.f;
        for (int c = 0; c < NC; c++) s += expf(lg[c] - m);
        red = m + logf(s);
    }
    __syncthreads();
    if (f < NC) out[g * NC + f] = lg[f] - red;
}

extern "C" void kernel_launch(void* const* d_in, const int* in_sizes, int n_in,
                              void* d_out, int out_size, void* d_ws, size_t ws_size,
                              hipStream_t stream) {
    const float* x     = (const float*)d_in[0];
    const int*   ei    = (const int*)d_in[1];
    const int*   srcp  = ei;
    const int*   dstp  = ei + NE;
    const int*   batch = (const int*)d_in[2];
    const float* W[3]  = {(const float*)d_in[3],  (const float*)d_in[7],  (const float*)d_in[11]};
    const float* b[3]  = {(const float*)d_in[4],  (const float*)d_in[8],  (const float*)d_in[12]};
    const float* gm[3] = {(const float*)d_in[5],  (const float*)d_in[9],  (const float*)d_in[13]};
    const float* bt[3] = {(const float*)d_in[6],  (const float*)d_in[10], (const float*)d_in[14]};
    const float* w1 = (const float*)d_in[15];
    const float* b1 = (const float*)d_in[16];
    const float* w2 = (const float*)d_in[17];
    const float* b2 = (const float*)d_in[18];
    float* out = (float*)d_out;

    // workspace layout (offsets in floats; float4/uint4 users at 16B-aligned offsets)
    float* ws       = (float*)d_ws;
    float* dis      = ws;                          // 100000
    int*   deg_i    = (int*)(ws + 100000);         // 100000 (doubles as cursor)
    int*   rowptr   = (int*)(ws + 200000);         // 100004
    int*   partials = (int*)(ws + 300004);         // 128
    int*   gstart   = (int*)(ws + 300132);         // 104
    float* sums     = ws + 300236;                 // 256
    float* ssbuf    = ws + 300492;                 // 3 * 256
    float* pooled   = ws + 301260;                 // 12800
    _Float16* wt    = (_Float16*)(ws + 314060);    // 3 * 16384 halves = 24576 floats
    int*   col      = (int*)(ws + 338636);         // NE
    float* aggbuf   = ws + 1938636;                // NN*H f32
    _Float16* hb    = (_Float16*)(ws + 14738636);  // NN*H f16

    const int nScanBlocks = (NN + 1023) / 1024;  // 98

    hipMemsetAsync(deg_i, 0, NN * sizeof(int), stream);
    k_deg<<<(NE + 255) / 256, 256, 0, stream>>>(dstp, deg_i);
    k_dis<<<(NN + 255) / 256, 256, 0, stream>>>(deg_i, dis);
    k_scan1<<<nScanBlocks, 256, 0, stream>>>(deg_i, rowptr, partials);
    k_scan2<<<1, 128, 0, stream>>>(partials, nScanBlocks);
    k_scan3<<<(NN + 255) / 256, 256, 0, stream>>>(rowptr, partials, deg_i /*cursor*/);
    k_fill<<<(NE + 255) / 256, 256, 0, stream>>>(srcp, dstp, deg_i, col);
    k_gstart<<<1, 128, 0, stream>>>(batch, gstart);
    for (int l = 0; l < 3; l++)
        k_prepw<<<64, 256, 0, stream>>>(W[l], wt + l * 16384);

    const float* xin = x;
    const float* ss_prev = nullptr;
    for (int l = 0; l < 3; l++) {
        float* ss = ssbuf + l * 256;
        k_gemm<<<(NN + 63) / 64, 256, 0, stream>>>(xin, ss_prev, wt + l * 16384, hb);
        k_agg<<<NN / 8, 256, 0, stream>>>(hb, rowptr, col, dis, b[l], aggbuf);
        hipMemsetAsync(sums, 0, 256 * sizeof(float), stream);
        k_stats<<<1024, 128, 0, stream>>>(aggbuf, sums);
        k_scaleshift<<<1, 128, 0, stream>>>(sums, gm[l], bt[l], ss);
        xin = aggbuf;
        ss_prev = ss;
    }

    k_pool2<<<NG, 256, 0, stream>>>(aggbuf, ssbuf + 2 * 256, gstart, pooled);
    k_head<<<NG, 128, 0, stream>>>(pooled, w1, b1, w2, b2, out);
}

// Round 5
// 937.204 us; speedup vs baseline: 3.7531x; 1.0091x over previous
//
#include <hip/hip_runtime.h>
#include <math.h>

constexpr int NN = 100000;   // nodes
constexpr int NE = 1600000;  // edges
constexpr int H  = 128;      // feat/hidden
constexpr int NG = 100;      // graphs
constexpr int NC = 10;       // classes
constexpr int NB = 98;       // CSR buckets (dst >> 10)

typedef _Float16 half8 __attribute__((ext_vector_type(8)));
typedef _Float16 half4 __attribute__((ext_vector_type(4)));
typedef float    f32x4 __attribute__((ext_vector_type(4)));

// ---------------- degree (int) ----------------
__global__ void k_deg(const int* __restrict__ dst, int* __restrict__ deg) {
    int e = blockIdx.x * 256 + threadIdx.x;
    if (e < NE) atomicAdd(&deg[dst[e]], 1);
}

__global__ void k_dis(const int* __restrict__ deg, float* __restrict__ dis) {
    int i = blockIdx.x * 256 + threadIdx.x;
    if (i < NN) dis[i] = rsqrtf((float)deg[i] + 1.0f);  // +1 self loop
}

// ---------------- exclusive scan of deg -> rowptr ----------------
__global__ __launch_bounds__(256) void k_scan1(const int* __restrict__ deg, int* __restrict__ out,
                                               int* __restrict__ partials) {
    __shared__ int tsum[256];
    int base = blockIdx.x * 1024;
    int tid = threadIdx.x;
    int v[4]; int s = 0;
    #pragma unroll
    for (int k = 0; k < 4; k++) {
        int i = base + tid * 4 + k;
        v[k] = (i < NN) ? deg[i] : 0;
        s += v[k];
    }
    tsum[tid] = s;
    __syncthreads();
    for (int off = 1; off < 256; off <<= 1) {
        int t = (tid >= off) ? tsum[tid - off] : 0;
        __syncthreads();
        tsum[tid] += t;
        __syncthreads();
    }
    int run = (tid == 0) ? 0 : tsum[tid - 1];
    #pragma unroll
    for (int k = 0; k < 4; k++) {
        int i = base + tid * 4 + k;
        if (i < NN) out[i] = run;
        run += v[k];
    }
    if (tid == 255) partials[blockIdx.x] = tsum[255];
}

__global__ void k_scan2(int* __restrict__ partials, int nb) {
    __shared__ int s[128];
    int tid = threadIdx.x;
    s[tid] = (tid < nb) ? partials[tid] : 0;
    __syncthreads();
    if (tid == 0) { int run = 0; for (int i = 0; i < nb; i++) { int t = s[i]; s[i] = run; run += t; } }
    __syncthreads();
    if (tid < nb) partials[tid] = s[tid];
}

__global__ void k_scan3(int* __restrict__ rowptr, const int* __restrict__ partials,
                        int* __restrict__ cursor) {
    int i = blockIdx.x * 256 + threadIdx.x;
    if (i < NN) {
        int v = rowptr[i] + partials[i >> 10];
        rowptr[i] = v;
        cursor[i] = v;
    }
    if (i == 0) rowptr[NN] = NE;
}

// ---------------- graph boundaries + bucket cursors ----------------
__global__ void k_gstart(const int* __restrict__ batch, int* __restrict__ gstart,
                         const int* __restrict__ rowptr, int* __restrict__ bcur) {
    int g = threadIdx.x;  // 128 threads
    if (g < NB) bcur[g] = rowptr[g << 10];  // staging mirrors col layout
    if (g > NG) return;
    if (g == NG) { gstart[g] = NN; return; }
    int lo = 0, hi = NN;
    while (lo < hi) { int mid = (lo + hi) >> 1; if (batch[mid] < g) lo = mid + 1; else hi = mid; }
    gstart[g] = lo;
}

// ---------------- CSR build pass 1: bin edges into 1024-node buckets ----------------
// 8192 edges per workgroup; LDS hist -> one global reservation per bucket -> grouped writes.
__global__ __launch_bounds__(256) void k_bucket1(const int* __restrict__ src,
                                                 const int* __restrict__ dst,
                                                 int* __restrict__ bcur,
                                                 int2* __restrict__ staging) {
    __shared__ int hist[NB];
    __shared__ int base[NB];
    int tid = threadIdx.x;
    int chunk0 = blockIdx.x * 8192;
    if (tid < NB) hist[tid] = 0;
    __syncthreads();
    for (int i = tid; i < 8192; i += 256) {
        int e = chunk0 + i;
        if (e < NE) atomicAdd(&hist[dst[e] >> 10], 1);
    }
    __syncthreads();
    if (tid < NB) { base[tid] = atomicAdd(&bcur[tid], hist[tid]); hist[tid] = 0; }
    __syncthreads();
    for (int i = tid; i < 8192; i += 256) {
        int e = chunk0 + i;
        if (e < NE) {
            int d = dst[e];
            int b = d >> 10;
            int off = atomicAdd(&hist[b], 1);
            staging[base[b] + off] = make_int2(src[e], d);
        }
    }
}

// ---------------- CSR build pass 2: bucket-local scatter (L2-resident window) ----------------
__global__ __launch_bounds__(256) void k_bucket2(const int2* __restrict__ staging,
                                                 const int* __restrict__ rowptr,
                                                 int* __restrict__ cursor,
                                                 int* __restrict__ col) {
    int b = blockIdx.x >> 2, q = blockIdx.x & 3;
    int nend = (b + 1) << 10; if (nend > NN) nend = NN;
    int s0 = rowptr[b << 10], s1 = rowptr[nend];
    for (int i = s0 + q * 256 + threadIdx.x; i < s1; i += 1024) {
        int2 e = staging[i];
        int pos = atomicAdd(&cursor[e.y], 1);
        col[pos] = e.x;
    }
}

// ---------------- W -> Wt (transposed, f16) once per layer ----------------
__global__ void k_prepw(const float* __restrict__ W, _Float16* __restrict__ Wt) {
    int idx = blockIdx.x * 256 + threadIdx.x;  // 16384
    int n = idx >> 7, k = idx & 127;
    Wt[idx] = (_Float16)W[k * 128 + n];
}

// ---------------- MFMA GEMM: Y_f16 = relu(X*scale+shift) @ W ----------------
// Layer 0: Xf (f32, no BN). Layers 1,2: Xh (f16) with ss (BN+ReLU fused in staging).
__global__ __launch_bounds__(256) void k_gemm(const float* __restrict__ Xf,
                                              const _Float16* __restrict__ Xh,
                                              const float* __restrict__ ss,
                                              const _Float16* __restrict__ Wt,
                                              _Float16* __restrict__ Y) {
    __shared__ _Float16 Wl[128][136];
    __shared__ _Float16 Xl[64][136];
    int tid = threadIdx.x;
    int row0 = blockIdx.x * 64;

    #pragma unroll
    for (int p = 0; p < 8; p++) {
        int idx = p * 2048 + tid * 8;
        int r = idx >> 7, c = idx & 127;
        *(uint4*)&Wl[r][c] = ((const uint4*)Wt)[idx >> 3];
    }
    if (Xh) {
        #pragma unroll
        for (int p = 0; p < 4; p++) {
            int idx = p * 2048 + tid * 8;
            int r = idx >> 7, c = idx & 127;
            int gr = row0 + r;
            half8 hv = {};
            if (gr < NN) hv = *(const half8*)&Xh[(size_t)gr * H + c];
            float4 sc0 = ((const float4*)ss)[c >> 2];
            float4 sc1 = ((const float4*)ss)[(c >> 2) + 1];
            float4 sh0 = ((const float4*)(ss + 128))[c >> 2];
            float4 sh1 = ((const float4*)(ss + 128))[(c >> 2) + 1];
            half8 o;
            o[0] = (_Float16)fmaxf((float)hv[0] * sc0.x + sh0.x, 0.f);
            o[1] = (_Float16)fmaxf((float)hv[1] * sc0.y + sh0.y, 0.f);
            o[2] = (_Float16)fmaxf((float)hv[2] * sc0.z + sh0.z, 0.f);
            o[3] = (_Float16)fmaxf((float)hv[3] * sc0.w + sh0.w, 0.f);
            o[4] = (_Float16)fmaxf((float)hv[4] * sc1.x + sh1.x, 0.f);
            o[5] = (_Float16)fmaxf((float)hv[5] * sc1.y + sh1.y, 0.f);
            o[6] = (_Float16)fmaxf((float)hv[6] * sc1.z + sh1.z, 0.f);
            o[7] = (_Float16)fmaxf((float)hv[7] * sc1.w + sh1.w, 0.f);
            *(half8*)&Xl[r][c] = o;
        }
    } else {
        #pragma unroll
        for (int p = 0; p < 8; p++) {
            int idx = p * 1024 + tid * 4;
            int r = idx >> 7, c = idx & 127;
            int gr = row0 + r;
            float4 v = make_float4(0.f, 0.f, 0.f, 0.f);
            if (gr < NN) v = *(const float4*)&Xf[(size_t)gr * H + c];
            half4 hv = {(_Float16)v.x, (_Float16)v.y, (_Float16)v.z, (_Float16)v.w};
            *(half4*)&Xl[r][c] = hv;
        }
    }
    __syncthreads();

    int wave = tid >> 6;
    int lane = tid & 63;
    int m = lane & 15;
    int quad = lane >> 4;

    half8 afrag[4];
    #pragma unroll
    for (int kc = 0; kc < 4; kc++)
        afrag[kc] = *(const half8*)&Xl[wave * 16 + m][kc * 32 + quad * 8];

    f32x4 acc[8];
    #pragma unroll
    for (int nt = 0; nt < 8; nt++) acc[nt] = (f32x4){0.f, 0.f, 0.f, 0.f};

    #pragma unroll
    for (int kc = 0; kc < 4; kc++) {
        #pragma unroll
        for (int nt = 0; nt < 8; nt++) {
            half8 b = *(const half8*)&Wl[nt * 16 + m][kc * 32 + quad * 8];
            acc[nt] = __builtin_amdgcn_mfma_f32_16x16x32_f16(afrag[kc], b, acc[nt], 0, 0, 0);
        }
    }

    #pragma unroll
    for (int nt = 0; nt < 8; nt++) {
        int c = nt * 16 + m;
        #pragma unroll
        for (int r = 0; r < 4; r++) {
            int gr = row0 + wave * 16 + quad * 4 + r;
            if (gr < NN) Y[(size_t)gr * H + c] = (_Float16)acc[nt][r];
        }
    }
}

// ---------------- gather-side aggregate (f16 h in, f16 agg out) ----------------
__global__ __launch_bounds__(256) void k_agg(const _Float16* __restrict__ h,
                                             const int* __restrict__ rowptr,
                                             const int* __restrict__ col,
                                             const float* __restrict__ dis,
                                             const float* __restrict__ bias,
                                             _Float16* __restrict__ out) {
    int node = blockIdx.x * 8 + (threadIdx.x >> 5);
    int lane = threadIdx.x & 31;
    int beg = rowptr[node], end = rowptr[node + 1];
    float dd = dis[node];
    const half4* h4 = (const half4*)h;
    half4 a = h4[(size_t)node * 32 + lane];
    float4 acc = make_float4((float)a.x * dd, (float)a.y * dd, (float)a.z * dd, (float)a.w * dd);
    for (int j = beg; j < end; j++) {
        int s = col[j];
        float ds = dis[s];
        half4 v = h4[(size_t)s * 32 + lane];
        acc.x += (float)v.x * ds; acc.y += (float)v.y * ds;
        acc.z += (float)v.z * ds; acc.w += (float)v.w * ds;
    }
    float4 bb = ((const float4*)bias)[lane];
    half4 o = {(_Float16)(acc.x * dd + bb.x), (_Float16)(acc.y * dd + bb.y),
               (_Float16)(acc.z * dd + bb.z), (_Float16)(acc.w * dd + bb.w)};
    ((half4*)out)[(size_t)node * 32 + lane] = o;
}

// ---------------- BN stats, two-stage (no contended atomics) ----------------
__global__ __launch_bounds__(128) void k_stats_a(const _Float16* __restrict__ x,
                                                 float* __restrict__ part) {
    int blk = blockIdx.x;  // 512 blocks x 196 rows
    int f = threadIdx.x;   // 128
    int r0 = blk * 196, r1 = r0 + 196 < NN ? r0 + 196 : NN;
    float s = 0.f, s2 = 0.f;
    for (int r = r0; r < r1; r++) {
        float v = (float)x[(size_t)r * H + f];
        s += v; s2 += v * v;
    }
    part[blk * 256 + f] = s;
    part[blk * 256 + 128 + f] = s2;
}

__global__ __launch_bounds__(256) void k_stats_b(const float* __restrict__ part,
                                                 float* __restrict__ sums) {
    int c = threadIdx.x;  // 256
    float a = 0.f;
    for (int i = 0; i < 512; i++) a += part[i * 256 + c];
    sums[c] = a;
}

__global__ void k_scaleshift(const float* __restrict__ sums, const float* __restrict__ gamma,
                             const float* __restrict__ beta, float* __restrict__ ss) {
    int f = threadIdx.x;
    float mean = sums[f] * (1.0f / NN);
    float var  = sums[128 + f] * (1.0f / NN) - mean * mean;
    float sc   = gamma[f] * rsqrtf(var + 1e-5f);
    ss[f] = sc;
    ss[128 + f] = beta[f] - mean * sc;
}

// ---------------- mean pool with fused BN+ReLU; one block per graph ----------------
__global__ __launch_bounds__(256) void k_pool2(const _Float16* __restrict__ x,
                                               const float* __restrict__ ss,
                                               const int* __restrict__ gstart,
                                               float* __restrict__ pooled) {
    int g = blockIdx.x;
    int beg = gstart[g], end = gstart[g + 1];
    int lane = threadIdx.x & 31;
    int walker = threadIdx.x >> 5;
    const half4* x4 = (const half4*)x;
    float4 sc = ((const float4*)ss)[lane];
    float4 sh = ((const float4*)(ss + 128))[lane];
    float4 acc = make_float4(0.f, 0.f, 0.f, 0.f);
    for (int r = beg + walker; r < end; r += 8) {
        half4 v = x4[(size_t)r * 32 + lane];
        acc.x += fmaxf((float)v.x * sc.x + sh.x, 0.f);
        acc.y += fmaxf((float)v.y * sc.y + sh.y, 0.f);
        acc.z += fmaxf((float)v.z * sc.z + sh.z, 0.f);
        acc.w += fmaxf((float)v.w * sc.w + sh.w, 0.f);
    }
    __shared__ float4 red[256];
    red[threadIdx.x] = acc;
    __syncthreads();
    if (threadIdx.x < 32) {
        float4 s = red[threadIdx.x];
        for (int w = 1; w < 8; w++) {
            float4 v = red[w * 32 + threadIdx.x];
            s.x += v.x; s.y += v.y; s.z += v.z; s.w += v.w;
        }
        float inv = 1.0f / fmaxf((float)(end - beg), 1.0f);
        ((float4*)pooled)[g * 32 + threadIdx.x] =
            make_float4(s.x * inv, s.y * inv, s.z * inv, s.w * inv);
    }
}

// ---------------- MLP head + log_softmax ----------------
__global__ __launch_bounds__(128) void k_head(const float* __restrict__ pooled,
                                              const float* __restrict__ w1, const float* __restrict__ b1,
                                              const float* __restrict__ w2, const float* __restrict__ b2,
                                              float* __restrict__ out) {
    __shared__ float p[H], hh[H], lg[NC], red;
    int g = blockIdx.x, f = threadIdx.x;
    p[f] = pooled[g * H + f];
    __syncthreads();
    float a = b1[f];
    for (int k = 0; k < H; k++) a += p[k] * w1[k * H + f];
    hh[f] = a > 0.f ? a : 0.f;
    __syncthreads();
    if (f < NC) {
        float l = b2[f];
        for (int k = 0; k < H; k++) l += hh[k] * w2[k * NC + f];
        lg[f] = l;
    }
    __syncthreads();
    if (f == 0) {
        float m = lg[0];
        for (int c = 1; c < NC; c++) m = m > lg[c] ? m : lg[c];
        float s = 0.f;
        for (int c = 0; c < NC; c++) s += expf(lg[c] - m);
        red = m + logf(s);
    }
    __syncthreads();
    if (f < NC) out[g * NC + f] = lg[f] - red;
}

extern "C" void kernel_launch(void* const* d_in, const int* in_sizes, int n_in,
                              void* d_out, int out_size, void* d_ws, size_t ws_size,
                              hipStream_t stream) {
    const float* x     = (const float*)d_in[0];
    const int*   ei    = (const int*)d_in[1];
    const int*   srcp  = ei;
    const int*   dstp  = ei + NE;
    const int*   batch = (const int*)d_in[2];
    const float* W[3]  = {(const float*)d_in[3],  (const float*)d_in[7],  (const float*)d_in[11]};
    const float* b[3]  = {(const float*)d_in[4],  (const float*)d_in[8],  (const float*)d_in[12]};
    const float* gm[3] = {(const float*)d_in[5],  (const float*)d_in[9],  (const float*)d_in[13]};
    const float* bt[3] = {(const float*)d_in[6],  (const float*)d_in[10], (const float*)d_in[14]};
    const float* w1 = (const float*)d_in[15];
    const float* b1 = (const float*)d_in[16];
    const float* w2 = (const float*)d_in[17];
    const float* b2 = (const float*)d_in[18];
    float* out = (float*)d_out;

    // workspace layout (float offsets; vector users 16B-aligned)
    float* ws        = (float*)d_ws;
    float* dis       = ws;                          // 100000
    int*   deg_i     = (int*)(ws + 100000);         // 100000 (doubles as cursor)
    int*   rowptr    = (int*)(ws + 200000);         // 100004
    int*   partials  = (int*)(ws + 300004);         // 128
    int*   gstart    = (int*)(ws + 300132);         // 104
    int*   bcur      = (int*)(ws + 300236);         // 128
    float* sums      = ws + 300364;                 // 256
    float* ssbuf     = ws + 300620;                 // 768
    float* pooled    = ws + 301388;                 // 12800
    float* sp        = ws + 314188;                 // 131072 (stats partials)
    _Float16* wt     = (_Float16*)(ws + 445260);    // 3*16384 halves
    int*   col       = (int*)(ws + 469836);         // NE
    int2*  staging   = (int2*)(ws + 2069836);       // NE int2
    _Float16* aggh   = (_Float16*)(ws + 5269836);   // NN*H f16
    _Float16* hb     = (_Float16*)(ws + 11669836);  // NN*H f16

    const int nScanBlocks = (NN + 1023) / 1024;  // 98

    hipMemsetAsync(deg_i, 0, NN * sizeof(int), stream);
    k_deg<<<(NE + 255) / 256, 256, 0, stream>>>(dstp, deg_i);
    k_dis<<<(NN + 255) / 256, 256, 0, stream>>>(deg_i, dis);
    k_scan1<<<nScanBlocks, 256, 0, stream>>>(deg_i, rowptr, partials);
    k_scan2<<<1, 128, 0, stream>>>(partials, nScanBlocks);
    k_scan3<<<(NN + 255) / 256, 256, 0, stream>>>(rowptr, partials, deg_i /*cursor*/);
    k_gstart<<<1, 128, 0, stream>>>(batch, gstart, rowptr, bcur);
    k_bucket1<<<(NE + 8191) / 8192, 256, 0, stream>>>(srcp, dstp, bcur, staging);
    k_bucket2<<<NB * 4, 256, 0, stream>>>(staging, rowptr, deg_i, col);
    for (int l = 0; l < 3; l++)
        k_prepw<<<64, 256, 0, stream>>>(W[l], wt + l * 16384);

    const float* ss_prev = nullptr;
    for (int l = 0; l < 3; l++) {
        float* ss = ssbuf + l * 256;
        k_gemm<<<(NN + 63) / 64, 256, 0, stream>>>(l == 0 ? x : nullptr,
                                                   l == 0 ? nullptr : aggh,
                                                   ss_prev, wt + l * 16384, hb);
        k_agg<<<NN / 8, 256, 0, stream>>>(hb, rowptr, col, dis, b[l], aggh);
        k_stats_a<<<512, 128, 0, stream>>>(aggh, sp);
        k_stats_b<<<1, 256, 0, stream>>>(sp, sums);
        k_scaleshift<<<1, 128, 0, stream>>>(sums, gm[l], bt[l], ss);
        ss_prev = ss;
    }

    k_pool2<<<NG, 256, 0, stream>>>(aggh, ssbuf + 2 * 256, gstart, pooled);
    k_head<<<NG, 128, 0, stream>>>(pooled, w1, b1, w2, b2, out);
}

// Round 6
// 872.907 us; speedup vs baseline: 4.0295x; 1.0737x over previous
//
#include <hip/hip_runtime.h>
#include <math.h>

constexpr int NN = 100000;   // nodes
constexpr int NE = 1600000;  // edges
constexpr int H  = 128;      // feat/hidden
constexpr int NG = 100;      // graphs
constexpr int NC = 10;       // classes
constexpr int NB = 98;       // CSR buckets (dst >> 10)

typedef _Float16 half8 __attribute__((ext_vector_type(8)));
typedef _Float16 half4 __attribute__((ext_vector_type(4)));
typedef float    f32x4 __attribute__((ext_vector_type(4)));

// ---------------- degree (int) ----------------
__global__ void k_deg(const int* __restrict__ dst, int* __restrict__ deg) {
    int e = blockIdx.x * 256 + threadIdx.x;
    if (e < NE) atomicAdd(&deg[dst[e]], 1);
}

__global__ void k_dis(const int* __restrict__ deg, float* __restrict__ dis) {
    int i = blockIdx.x * 256 + threadIdx.x;
    if (i < NN) dis[i] = rsqrtf((float)deg[i] + 1.0f);  // +1 self loop
}

// ---------------- exclusive scan of deg -> rowptr ----------------
__global__ __launch_bounds__(256) void k_scan1(const int* __restrict__ deg, int* __restrict__ out,
                                               int* __restrict__ partials) {
    __shared__ int tsum[256];
    int base = blockIdx.x * 1024;
    int tid = threadIdx.x;
    int v[4]; int s = 0;
    #pragma unroll
    for (int k = 0; k < 4; k++) {
        int i = base + tid * 4 + k;
        v[k] = (i < NN) ? deg[i] : 0;
        s += v[k];
    }
    tsum[tid] = s;
    __syncthreads();
    for (int off = 1; off < 256; off <<= 1) {
        int t = (tid >= off) ? tsum[tid - off] : 0;
        __syncthreads();
        tsum[tid] += t;
        __syncthreads();
    }
    int run = (tid == 0) ? 0 : tsum[tid - 1];
    #pragma unroll
    for (int k = 0; k < 4; k++) {
        int i = base + tid * 4 + k;
        if (i < NN) out[i] = run;
        run += v[k];
    }
    if (tid == 255) partials[blockIdx.x] = tsum[255];
}

__global__ void k_scan2(int* __restrict__ partials, int nb) {
    __shared__ int s[128];
    int tid = threadIdx.x;
    s[tid] = (tid < nb) ? partials[tid] : 0;
    __syncthreads();
    if (tid == 0) { int run = 0; for (int i = 0; i < nb; i++) { int t = s[i]; s[i] = run; run += t; } }
    __syncthreads();
    if (tid < nb) partials[tid] = s[tid];
}

__global__ void k_scan3(int* __restrict__ rowptr, const int* __restrict__ partials,
                        int* __restrict__ cursor) {
    int i = blockIdx.x * 256 + threadIdx.x;
    if (i < NN) {
        int v = rowptr[i] + partials[i >> 10];
        rowptr[i] = v;
        cursor[i] = v;
    }
    if (i == 0) rowptr[NN] = NE;
}

// ---------------- graph boundaries + bucket cursors ----------------
__global__ void k_gstart(const int* __restrict__ batch, int* __restrict__ gstart,
                         const int* __restrict__ rowptr, int* __restrict__ bcur) {
    int g = threadIdx.x;  // 128 threads
    if (g < NB) bcur[g] = rowptr[g << 10];
    if (g > NG) return;
    if (g == NG) { gstart[g] = NN; return; }
    int lo = 0, hi = NN;
    while (lo < hi) { int mid = (lo + hi) >> 1; if (batch[mid] < g) lo = mid + 1; else hi = mid; }
    gstart[g] = lo;
}

// ---------------- CSR build pass 1: bin edges into 1024-node buckets ----------------
__global__ __launch_bounds__(256) void k_bucket1(const int* __restrict__ src,
                                                 const int* __restrict__ dst,
                                                 int* __restrict__ bcur,
                                                 int2* __restrict__ staging) {
    __shared__ int hist[NB];
    __shared__ int base[NB];
    int tid = threadIdx.x;
    int chunk0 = blockIdx.x * 8192;
    if (tid < NB) hist[tid] = 0;
    __syncthreads();
    for (int i = tid; i < 8192; i += 256) {
        int e = chunk0 + i;
        if (e < NE) atomicAdd(&hist[dst[e] >> 10], 1);
    }
    __syncthreads();
    if (tid < NB) { base[tid] = atomicAdd(&bcur[tid], hist[tid]); hist[tid] = 0; }
    __syncthreads();
    for (int i = tid; i < 8192; i += 256) {
        int e = chunk0 + i;
        if (e < NE) {
            int d = dst[e];
            int b = d >> 10;
            int off = atomicAdd(&hist[b], 1);
            staging[base[b] + off] = make_int2(src[e], d);
        }
    }
}

// ---------------- CSR build pass 2: bucket-local scatter ----------------
__global__ __launch_bounds__(256) void k_bucket2(const int2* __restrict__ staging,
                                                 const int* __restrict__ rowptr,
                                                 int* __restrict__ cursor,
                                                 int* __restrict__ col) {
    int b = blockIdx.x >> 2, q = blockIdx.x & 3;
    int nend = (b + 1) << 10; if (nend > NN) nend = NN;
    int s0 = rowptr[b << 10], s1 = rowptr[nend];
    for (int i = s0 + q * 256 + threadIdx.x; i < s1; i += 1024) {
        int2 e = staging[i];
        int pos = atomicAdd(&cursor[e.y], 1);
        col[pos] = e.x;
    }
}

// ---------------- W -> Wt (transposed, f16) once per layer ----------------
__global__ void k_prepw(const float* __restrict__ W, _Float16* __restrict__ Wt) {
    int idx = blockIdx.x * 256 + threadIdx.x;  // 16384
    int n = idx >> 7, k = idx & 127;
    Wt[idx] = (_Float16)W[k * 128 + n];
}

// ---------------- MFMA GEMM: Y_f16 = (relu(X*scale+shift) @ W) * dis[row] ----------------
// Epilogue pre-scales by dis so k_agg's inner loop is a pure gather.
__global__ __launch_bounds__(256) void k_gemm(const float* __restrict__ Xf,
                                              const _Float16* __restrict__ Xh,
                                              const float* __restrict__ ss,
                                              const _Float16* __restrict__ Wt,
                                              const float* __restrict__ dis,
                                              _Float16* __restrict__ Y) {
    __shared__ _Float16 Wl[128][136];
    __shared__ _Float16 Xl[64][136];
    int tid = threadIdx.x;
    int row0 = blockIdx.x * 64;

    #pragma unroll
    for (int p = 0; p < 8; p++) {
        int idx = p * 2048 + tid * 8;
        int r = idx >> 7, c = idx & 127;
        *(uint4*)&Wl[r][c] = ((const uint4*)Wt)[idx >> 3];
    }
    if (Xh) {
        #pragma unroll
        for (int p = 0; p < 4; p++) {
            int idx = p * 2048 + tid * 8;
            int r = idx >> 7, c = idx & 127;
            int gr = row0 + r;
            half8 hv = {};
            if (gr < NN) hv = *(const half8*)&Xh[(size_t)gr * H + c];
            float4 sc0 = ((const float4*)ss)[c >> 2];
            float4 sc1 = ((const float4*)ss)[(c >> 2) + 1];
            float4 sh0 = ((const float4*)(ss + 128))[c >> 2];
            float4 sh1 = ((const float4*)(ss + 128))[(c >> 2) + 1];
            half8 o;
            o[0] = (_Float16)fmaxf((float)hv[0] * sc0.x + sh0.x, 0.f);
            o[1] = (_Float16)fmaxf((float)hv[1] * sc0.y + sh0.y, 0.f);
            o[2] = (_Float16)fmaxf((float)hv[2] * sc0.z + sh0.z, 0.f);
            o[3] = (_Float16)fmaxf((float)hv[3] * sc0.w + sh0.w, 0.f);
            o[4] = (_Float16)fmaxf((float)hv[4] * sc1.x + sh1.x, 0.f);
            o[5] = (_Float16)fmaxf((float)hv[5] * sc1.y + sh1.y, 0.f);
            o[6] = (_Float16)fmaxf((float)hv[6] * sc1.z + sh1.z, 0.f);
            o[7] = (_Float16)fmaxf((float)hv[7] * sc1.w + sh1.w, 0.f);
            *(half8*)&Xl[r][c] = o;
        }
    } else {
        #pragma unroll
        for (int p = 0; p < 8; p++) {
            int idx = p * 1024 + tid * 4;
            int r = idx >> 7, c = idx & 127;
            int gr = row0 + r;
            float4 v = make_float4(0.f, 0.f, 0.f, 0.f);
            if (gr < NN) v = *(const float4*)&Xf[(size_t)gr * H + c];
            half4 hv = {(_Float16)v.x, (_Float16)v.y, (_Float16)v.z, (_Float16)v.w};
            *(half4*)&Xl[r][c] = hv;
        }
    }
    __syncthreads();

    int wave = tid >> 6;
    int lane = tid & 63;
    int m = lane & 15;
    int quad = lane >> 4;

    half8 afrag[4];
    #pragma unroll
    for (int kc = 0; kc < 4; kc++)
        afrag[kc] = *(const half8*)&Xl[wave * 16 + m][kc * 32 + quad * 8];

    f32x4 acc[8];
    #pragma unroll
    for (int nt = 0; nt < 8; nt++) acc[nt] = (f32x4){0.f, 0.f, 0.f, 0.f};

    #pragma unroll
    for (int kc = 0; kc < 4; kc++) {
        #pragma unroll
        for (int nt = 0; nt < 8; nt++) {
            half8 b = *(const half8*)&Wl[nt * 16 + m][kc * 32 + quad * 8];
            acc[nt] = __builtin_amdgcn_mfma_f32_16x16x32_f16(afrag[kc], b, acc[nt], 0, 0, 0);
        }
    }

    float dv[4];
    #pragma unroll
    for (int r = 0; r < 4; r++) {
        int gr = row0 + wave * 16 + quad * 4 + r;
        dv[r] = (gr < NN) ? dis[gr] : 0.f;
    }
    #pragma unroll
    for (int nt = 0; nt < 8; nt++) {
        int c = nt * 16 + m;
        #pragma unroll
        for (int r = 0; r < 4; r++) {
            int gr = row0 + wave * 16 + quad * 4 + r;
            if (gr < NN) Y[(size_t)gr * H + c] = (_Float16)(acc[nt][r] * dv[r]);
        }
    }
}

// ---------------- gather-side aggregate: out = dis[d]*(h'[d] + sum h'[col]) + bias ----------------
// h' is pre-scaled by dis (gemm epilogue); inner loop = pure gather, unroll x4 for MLP.
__global__ __launch_bounds__(256) void k_agg(const _Float16* __restrict__ hs,
                                             const int* __restrict__ rowptr,
                                             const int* __restrict__ col,
                                             const float* __restrict__ dis,
                                             const float* __restrict__ bias,
                                             _Float16* __restrict__ out) {
    int node = blockIdx.x * 8 + (threadIdx.x >> 5);
    int lane = threadIdx.x & 31;
    int beg = rowptr[node], end = rowptr[node + 1];
    float dd = dis[node];
    const half4* h4 = (const half4*)hs;
    half4 a = h4[(size_t)node * 32 + lane];
    float4 acc = make_float4((float)a.x, (float)a.y, (float)a.z, (float)a.w);
    int j = beg;
    for (; j + 3 < end; j += 4) {
        int c0 = col[j], c1 = col[j + 1], c2 = col[j + 2], c3 = col[j + 3];
        half4 v0 = h4[(size_t)c0 * 32 + lane];
        half4 v1 = h4[(size_t)c1 * 32 + lane];
        half4 v2 = h4[(size_t)c2 * 32 + lane];
        half4 v3 = h4[(size_t)c3 * 32 + lane];
        acc.x += ((float)v0.x + (float)v1.x) + ((float)v2.x + (float)v3.x);
        acc.y += ((float)v0.y + (float)v1.y) + ((float)v2.y + (float)v3.y);
        acc.z += ((float)v0.z + (float)v1.z) + ((float)v2.z + (float)v3.z);
        acc.w += ((float)v0.w + (float)v1.w) + ((float)v2.w + (float)v3.w);
    }
    for (; j < end; j++) {
        half4 v = h4[(size_t)col[j] * 32 + lane];
        acc.x += (float)v.x; acc.y += (float)v.y;
        acc.z += (float)v.z; acc.w += (float)v.w;
    }
    float4 bb = ((const float4*)bias)[lane];
    half4 o = {(_Float16)(acc.x * dd + bb.x), (_Float16)(acc.y * dd + bb.y),
               (_Float16)(acc.z * dd + bb.z), (_Float16)(acc.w * dd + bb.w)};
    ((half4*)out)[(size_t)node * 32 + lane] = o;
}

// ---------------- BN stats, two-stage ----------------
__global__ __launch_bounds__(128) void k_stats_a(const _Float16* __restrict__ x,
                                                 float* __restrict__ part) {
    int blk = blockIdx.x;  // 512 blocks x 196 rows
    int f = threadIdx.x;   // 128
    int r0 = blk * 196, r1 = r0 + 196 < NN ? r0 + 196 : NN;
    float s = 0.f, s2 = 0.f;
    for (int r = r0; r < r1; r++) {
        float v = (float)x[(size_t)r * H + f];
        s += v; s2 += v * v;
    }
    part[blk * 256 + f] = s;
    part[blk * 256 + 128 + f] = s2;
}

__global__ __launch_bounds__(256) void k_stats_b(const float* __restrict__ part,
                                                 float* __restrict__ sums) {
    int c = threadIdx.x;  // 256
    float a = 0.f;
    for (int i = 0; i < 512; i++) a += part[i * 256 + c];
    sums[c] = a;
}

__global__ void k_scaleshift(const float* __restrict__ sums, const float* __restrict__ gamma,
                             const float* __restrict__ beta, float* __restrict__ ss) {
    int f = threadIdx.x;
    float mean = sums[f] * (1.0f / NN);
    float var  = sums[128 + f] * (1.0f / NN) - mean * mean;
    float sc   = gamma[f] * rsqrtf(var + 1e-5f);
    ss[f] = sc;
    ss[128 + f] = beta[f] - mean * sc;
}

// ---------------- mean pool with fused BN+ReLU ----------------
__global__ __launch_bounds__(256) void k_pool2(const _Float16* __restrict__ x,
                                               const float* __restrict__ ss,
                                               const int* __restrict__ gstart,
                                               float* __restrict__ pooled) {
    int g = blockIdx.x;
    int beg = gstart[g], end = gstart[g + 1];
    int lane = threadIdx.x & 31;
    int walker = threadIdx.x >> 5;
    const half4* x4 = (const half4*)x;
    float4 sc = ((const float4*)ss)[lane];
    float4 sh = ((const float4*)(ss + 128))[lane];
    float4 acc = make_float4(0.f, 0.f, 0.f, 0.f);
    for (int r = beg + walker; r < end; r += 8) {
        half4 v = x4[(size_t)r * 32 + lane];
        acc.x += fmaxf((float)v.x * sc.x + sh.x, 0.f);
        acc.y += fmaxf((float)v.y * sc.y + sh.y, 0.f);
        acc.z += fmaxf((float)v.z * sc.z + sh.z, 0.f);
        acc.w += fmaxf((float)v.w * sc.w + sh.w, 0.f);
    }
    __shared__ float4 red[256];
    red[threadIdx.x] = acc;
    __syncthreads();
    if (threadIdx.x < 32) {
        float4 s = red[threadIdx.x];
        for (int w = 1; w < 8; w++) {
            float4 v = red[w * 32 + threadIdx.x];
            s.x += v.x; s.y += v.y; s.z += v.z; s.w += v.w;
        }
        float inv = 1.0f / fmaxf((float)(end - beg), 1.0f);
        ((float4*)pooled)[g * 32 + threadIdx.x] =
            make_float4(s.x * inv, s.y * inv, s.z * inv, s.w * inv);
    }
}

// ---------------- MLP head + log_softmax ----------------
__global__ __launch_bounds__(128) void k_head(const float* __restrict__ pooled,
                                              const float* __restrict__ w1, const float* __restrict__ b1,
                                              const float* __restrict__ w2, const float* __restrict__ b2,
                                              float* __restrict__ out) {
    __shared__ float p[H], hh[H], lg[NC], red;
    int g = blockIdx.x, f = threadIdx.x;
    p[f] = pooled[g * H + f];
    __syncthreads();
    float a = b1[f];
    for (int k = 0; k < H; k++) a += p[k] * w1[k * H + f];
    hh[f] = a > 0.f ? a : 0.f;
    __syncthreads();
    if (f < NC) {
        float l = b2[f];
        for (int k = 0; k < H; k++) l += hh[k] * w2[k * NC + f];
        lg[f] = l;
    }
    __syncthreads();
    if (f == 0) {
        float m = lg[0];
        for (int c = 1; c < NC; c++) m = m > lg[c] ? m : lg[c];
        float s = 0.f;
        for (int c = 0; c < NC; c++) s += expf(lg[c] - m);
        red = m + logf(s);
    }
    __syncthreads();
    if (f < NC) out[g * NC + f] = lg[f] - red;
}

extern "C" void kernel_launch(void* const* d_in, const int* in_sizes, int n_in,
                              void* d_out, int out_size, void* d_ws, size_t ws_size,
                              hipStream_t stream) {
    const float* x     = (const float*)d_in[0];
    const int*   ei    = (const int*)d_in[1];
    const int*   srcp  = ei;
    const int*   dstp  = ei + NE;
    const int*   batch = (const int*)d_in[2];
    const float* W[3]  = {(const float*)d_in[3],  (const float*)d_in[7],  (const float*)d_in[11]};
    const float* b[3]  = {(const float*)d_in[4],  (const float*)d_in[8],  (const float*)d_in[12]};
    const float* gm[3] = {(const float*)d_in[5],  (const float*)d_in[9],  (const float*)d_in[13]};
    const float* bt[3] = {(const float*)d_in[6],  (const float*)d_in[10], (const float*)d_in[14]};
    const float* w1 = (const float*)d_in[15];
    const float* b1 = (const float*)d_in[16];
    const float* w2 = (const float*)d_in[17];
    const float* b2 = (const float*)d_in[18];
    float* out = (float*)d_out;

    float* ws        = (float*)d_ws;
    float* dis       = ws;                          // 100000
    int*   deg_i     = (int*)(ws + 100000);         // 100000 (doubles as cursor)
    int*   rowptr    = (int*)(ws + 200000);         // 100004
    int*   partials  = (int*)(ws + 300004);         // 128
    int*   gstart    = (int*)(ws + 300132);         // 104
    int*   bcur      = (int*)(ws + 300236);         // 128
    float* sums      = ws + 300364;                 // 256
    float* ssbuf     = ws + 300620;                 // 768
    float* pooled    = ws + 301388;                 // 12800
    float* sp        = ws + 314188;                 // 131072 (stats partials)
    _Float16* wt     = (_Float16*)(ws + 445260);    // 3*16384 halves
    int*   col       = (int*)(ws + 469836);         // NE
    int2*  staging   = (int2*)(ws + 2069836);       // NE int2
    _Float16* aggh   = (_Float16*)(ws + 5269836);   // NN*H f16
    _Float16* hb     = (_Float16*)(ws + 11669836);  // NN*H f16

    const int nScanBlocks = (NN + 1023) / 1024;  // 98

    hipMemsetAsync(deg_i, 0, NN * sizeof(int), stream);
    k_deg<<<(NE + 255) / 256, 256, 0, stream>>>(dstp, deg_i);
    k_dis<<<(NN + 255) / 256, 256, 0, stream>>>(deg_i, dis);
    k_scan1<<<nScanBlocks, 256, 0, stream>>>(deg_i, rowptr, partials);
    k_scan2<<<1, 128, 0, stream>>>(partials, nScanBlocks);
    k_scan3<<<(NN + 255) / 256, 256, 0, stream>>>(rowptr, partials, deg_i /*cursor*/);
    k_gstart<<<1, 128, 0, stream>>>(batch, gstart, rowptr, bcur);
    k_bucket1<<<(NE + 8191) / 8192, 256, 0, stream>>>(srcp, dstp, bcur, staging);
    k_bucket2<<<NB * 4, 256, 0, stream>>>(staging, rowptr, deg_i, col);
    for (int l = 0; l < 3; l++)
        k_prepw<<<64, 256, 0, stream>>>(W[l], wt + l * 16384);

    const float* ss_prev = nullptr;
    for (int l = 0; l < 3; l++) {
        float* ss = ssbuf + l * 256;
        k_gemm<<<(NN + 63) / 64, 256, 0, stream>>>(l == 0 ? x : nullptr,
                                                   l == 0 ? nullptr : aggh,
                                                   ss_prev, wt + l * 16384, dis, hb);
        k_agg<<<NN / 8, 256, 0, stream>>>(hb, rowptr, col, dis, b[l], aggh);
        k_stats_a<<<512, 128, 0, stream>>>(aggh, sp);
        k_stats_b<<<1, 256, 0, stream>>>(sp, sums);
        k_scaleshift<<<1, 128, 0, stream>>>(sums, gm[l], bt[l], ss);
        ss_prev = ss;
    }

    k_pool2<<<NG, 256, 0, stream>>>(aggh, ssbuf + 2 * 256, gstart, pooled);
    k_head<<<NG, 128, 0, stream>>>(pooled, w1, b1, w2, b2, out);
}

// Round 7
// 862.571 us; speedup vs baseline: 4.0778x; 1.0120x over previous
//
#include <hip/hip_runtime.h>
#include <math.h>

constexpr int NN = 100000;   // nodes
constexpr int NE = 1600000;  // edges
constexpr int H  = 128;      // feat/hidden
constexpr int NG = 100;      // graphs
constexpr int NC = 10;       // classes
constexpr int NB = 98;       // CSR buckets (dst >> 10)

typedef _Float16 half8 __attribute__((ext_vector_type(8)));
typedef _Float16 half4 __attribute__((ext_vector_type(4)));
typedef float    f32x4 __attribute__((ext_vector_type(4)));

// ---------------- degree (int) ----------------
__global__ void k_deg(const int* __restrict__ dst, int* __restrict__ deg) {
    int e = blockIdx.x * 256 + threadIdx.x;
    if (e < NE) atomicAdd(&deg[dst[e]], 1);
}

// ---------------- scan pass 1 (+ dis = rsqrt(deg+1) fused) ----------------
__global__ __launch_bounds__(256) void k_scan1(const int* __restrict__ deg, int* __restrict__ out,
                                               int* __restrict__ partials, float* __restrict__ dis) {
    __shared__ int tsum[256];
    int base = blockIdx.x * 1024;
    int tid = threadIdx.x;
    int v[4]; int s = 0;
    #pragma unroll
    for (int k = 0; k < 4; k++) {
        int i = base + tid * 4 + k;
        v[k] = (i < NN) ? deg[i] : 0;
        if (i < NN) dis[i] = rsqrtf((float)v[k] + 1.0f);
        s += v[k];
    }
    tsum[tid] = s;
    __syncthreads();
    for (int off = 1; off < 256; off <<= 1) {
        int t = (tid >= off) ? tsum[tid - off] : 0;
        __syncthreads();
        tsum[tid] += t;
        __syncthreads();
    }
    int run = (tid == 0) ? 0 : tsum[tid - 1];
    #pragma unroll
    for (int k = 0; k < 4; k++) {
        int i = base + tid * 4 + k;
        if (i < NN) out[i] = run;
        run += v[k];
    }
    if (tid == 255) partials[blockIdx.x] = tsum[255];
}

// ---------------- scan pass 2 (block 0) + graph boundaries (block 1) ----------------
__global__ void k_scan2g(int* __restrict__ partials, int nb,
                         const int* __restrict__ batch, int* __restrict__ gstart) {
    int tid = threadIdx.x;
    if (blockIdx.x == 0) {
        __shared__ int s[128];
        s[tid] = (tid < nb) ? partials[tid] : 0;
        __syncthreads();
        if (tid == 0) { int run = 0; for (int i = 0; i < nb; i++) { int t = s[i]; s[i] = run; run += t; } }
        __syncthreads();
        if (tid < nb) partials[tid] = s[tid];
    } else {
        int g = tid;
        if (g > NG) return;
        if (g == NG) { gstart[g] = NN; return; }
        int lo = 0, hi = NN;
        while (lo < hi) { int mid = (lo + hi) >> 1; if (batch[mid] < g) lo = mid + 1; else hi = mid; }
        gstart[g] = lo;
    }
}

// ---------------- scan pass 3 (+ bucket cursor init fused) ----------------
__global__ void k_scan3(int* __restrict__ rowptr, const int* __restrict__ partials,
                        int* __restrict__ cursor, int* __restrict__ bcur) {
    int i = blockIdx.x * 256 + threadIdx.x;
    if (i < NN) {
        int v = rowptr[i] + partials[i >> 10];
        rowptr[i] = v;
        cursor[i] = v;
        if ((i & 1023) == 0) bcur[i >> 10] = v;
    }
    if (i == 0) rowptr[NN] = NE;
}

// ---------------- CSR build pass 1: bin edges into 1024-node buckets ----------------
__global__ __launch_bounds__(256) void k_bucket1(const int* __restrict__ src,
                                                 const int* __restrict__ dst,
                                                 int* __restrict__ bcur,
                                                 int2* __restrict__ staging) {
    __shared__ int hist[NB];
    __shared__ int base[NB];
    int tid = threadIdx.x;
    int chunk0 = blockIdx.x * 8192;
    if (tid < NB) hist[tid] = 0;
    __syncthreads();
    for (int i = tid; i < 8192; i += 256) {
        int e = chunk0 + i;
        if (e < NE) atomicAdd(&hist[dst[e] >> 10], 1);
    }
    __syncthreads();
    if (tid < NB) { base[tid] = atomicAdd(&bcur[tid], hist[tid]); hist[tid] = 0; }
    __syncthreads();
    for (int i = tid; i < 8192; i += 256) {
        int e = chunk0 + i;
        if (e < NE) {
            int d = dst[e];
            int b = d >> 10;
            int off = atomicAdd(&hist[b], 1);
            staging[base[b] + off] = make_int2(src[e], d);
        }
    }
}

// ---------------- CSR build pass 2: bucket-local scatter ----------------
__global__ __launch_bounds__(256) void k_bucket2(const int2* __restrict__ staging,
                                                 const int* __restrict__ rowptr,
                                                 int* __restrict__ cursor,
                                                 int* __restrict__ col) {
    int b = blockIdx.x >> 2, q = blockIdx.x & 3;
    int nend = (b + 1) << 10; if (nend > NN) nend = NN;
    int s0 = rowptr[b << 10], s1 = rowptr[nend];
    for (int i = s0 + q * 256 + threadIdx.x; i < s1; i += 1024) {
        int2 e = staging[i];
        int pos = atomicAdd(&cursor[e.y], 1);
        col[pos] = e.x;
    }
}

// ---------------- W -> Wt (transposed, f16), all 3 layers, one dispatch ----------------
__global__ void k_prepw3(const float* __restrict__ W0, const float* __restrict__ W1,
                         const float* __restrict__ W2, _Float16* __restrict__ Wt) {
    int gi = blockIdx.x * 256 + threadIdx.x;  // 3 * 16384
    int l = gi >> 14, idx = gi & 16383;
    const float* W = (l == 0) ? W0 : (l == 1) ? W1 : W2;
    int n = idx >> 7, k = idx & 127;
    Wt[gi] = (_Float16)W[k * 128 + n];
}

// ---------------- MFMA GEMM: Y_f16 = (relu(X*scale+shift) @ W) * dis[row] ----------------
__global__ __launch_bounds__(256) void k_gemm(const float* __restrict__ Xf,
                                              const _Float16* __restrict__ Xh,
                                              const float* __restrict__ ss,
                                              const _Float16* __restrict__ Wt,
                                              const float* __restrict__ dis,
                                              _Float16* __restrict__ Y) {
    __shared__ _Float16 Wl[128][136];
    __shared__ _Float16 Xl[64][136];
    int tid = threadIdx.x;
    int row0 = blockIdx.x * 64;

    #pragma unroll
    for (int p = 0; p < 8; p++) {
        int idx = p * 2048 + tid * 8;
        int r = idx >> 7, c = idx & 127;
        *(uint4*)&Wl[r][c] = ((const uint4*)Wt)[idx >> 3];
    }
    if (Xh) {
        #pragma unroll
        for (int p = 0; p < 4; p++) {
            int idx = p * 2048 + tid * 8;
            int r = idx >> 7, c = idx & 127;
            int gr = row0 + r;
            half8 hv = {};
            if (gr < NN) hv = *(const half8*)&Xh[(size_t)gr * H + c];
            float4 sc0 = ((const float4*)ss)[c >> 2];
            float4 sc1 = ((const float4*)ss)[(c >> 2) + 1];
            float4 sh0 = ((const float4*)(ss + 128))[c >> 2];
            float4 sh1 = ((const float4*)(ss + 128))[(c >> 2) + 1];
            half8 o;
            o[0] = (_Float16)fmaxf((float)hv[0] * sc0.x + sh0.x, 0.f);
            o[1] = (_Float16)fmaxf((float)hv[1] * sc0.y + sh0.y, 0.f);
            o[2] = (_Float16)fmaxf((float)hv[2] * sc0.z + sh0.z, 0.f);
            o[3] = (_Float16)fmaxf((float)hv[3] * sc0.w + sh0.w, 0.f);
            o[4] = (_Float16)fmaxf((float)hv[4] * sc1.x + sh1.x, 0.f);
            o[5] = (_Float16)fmaxf((float)hv[5] * sc1.y + sh1.y, 0.f);
            o[6] = (_Float16)fmaxf((float)hv[6] * sc1.z + sh1.z, 0.f);
            o[7] = (_Float16)fmaxf((float)hv[7] * sc1.w + sh1.w, 0.f);
            *(half8*)&Xl[r][c] = o;
        }
    } else {
        #pragma unroll
        for (int p = 0; p < 8; p++) {
            int idx = p * 1024 + tid * 4;
            int r = idx >> 7, c = idx & 127;
            int gr = row0 + r;
            float4 v = make_float4(0.f, 0.f, 0.f, 0.f);
            if (gr < NN) v = *(const float4*)&Xf[(size_t)gr * H + c];
            half4 hv = {(_Float16)v.x, (_Float16)v.y, (_Float16)v.z, (_Float16)v.w};
            *(half4*)&Xl[r][c] = hv;
        }
    }
    __syncthreads();

    int wave = tid >> 6;
    int lane = tid & 63;
    int m = lane & 15;
    int quad = lane >> 4;

    half8 afrag[4];
    #pragma unroll
    for (int kc = 0; kc < 4; kc++)
        afrag[kc] = *(const half8*)&Xl[wave * 16 + m][kc * 32 + quad * 8];

    f32x4 acc[8];
    #pragma unroll
    for (int nt = 0; nt < 8; nt++) acc[nt] = (f32x4){0.f, 0.f, 0.f, 0.f};

    #pragma unroll
    for (int kc = 0; kc < 4; kc++) {
        #pragma unroll
        for (int nt = 0; nt < 8; nt++) {
            half8 b = *(const half8*)&Wl[nt * 16 + m][kc * 32 + quad * 8];
            acc[nt] = __builtin_amdgcn_mfma_f32_16x16x32_f16(afrag[kc], b, acc[nt], 0, 0, 0);
        }
    }

    float dv[4];
    #pragma unroll
    for (int r = 0; r < 4; r++) {
        int gr = row0 + wave * 16 + quad * 4 + r;
        dv[r] = (gr < NN) ? dis[gr] : 0.f;
    }
    #pragma unroll
    for (int nt = 0; nt < 8; nt++) {
        int c = nt * 16 + m;
        #pragma unroll
        for (int r = 0; r < 4; r++) {
            int gr = row0 + wave * 16 + quad * 4 + r;
            if (gr < NN) Y[(size_t)gr * H + c] = (_Float16)(acc[nt][r] * dv[r]);
        }
    }
}

// ---------------- gather-side aggregate: out = dis[d]*(h'[d] + sum h'[col]) + bias ----------------
// h' pre-scaled by dis; unroll x8 for memory-level parallelism.
__global__ __launch_bounds__(256) void k_agg(const _Float16* __restrict__ hs,
                                             const int* __restrict__ rowptr,
                                             const int* __restrict__ col,
                                             const float* __restrict__ dis,
                                             const float* __restrict__ bias,
                                             _Float16* __restrict__ out) {
    int node = blockIdx.x * 8 + (threadIdx.x >> 5);
    int lane = threadIdx.x & 31;
    int beg = rowptr[node], end = rowptr[node + 1];
    float dd = dis[node];
    const half4* h4 = (const half4*)hs;
    half4 a = h4[(size_t)node * 32 + lane];
    float4 acc = make_float4((float)a.x, (float)a.y, (float)a.z, (float)a.w);
    int j = beg;
    for (; j + 8 <= end; j += 8) {
        int c[8];
        #pragma unroll
        for (int u = 0; u < 8; u++) c[u] = col[j + u];
        half4 v[8];
        #pragma unroll
        for (int u = 0; u < 8; u++) v[u] = h4[(size_t)c[u] * 32 + lane];
        #pragma unroll
        for (int u = 0; u < 8; u++) {
            acc.x += (float)v[u].x; acc.y += (float)v[u].y;
            acc.z += (float)v[u].z; acc.w += (float)v[u].w;
        }
    }
    for (; j + 2 <= end; j += 2) {
        int c0 = col[j], c1 = col[j + 1];
        half4 v0 = h4[(size_t)c0 * 32 + lane];
        half4 v1 = h4[(size_t)c1 * 32 + lane];
        acc.x += (float)v0.x + (float)v1.x; acc.y += (float)v0.y + (float)v1.y;
        acc.z += (float)v0.z + (float)v1.z; acc.w += (float)v0.w + (float)v1.w;
    }
    if (j < end) {
        half4 v = h4[(size_t)col[j] * 32 + lane];
        acc.x += (float)v.x; acc.y += (float)v.y;
        acc.z += (float)v.z; acc.w += (float)v.w;
    }
    float4 bb = ((const float4*)bias)[lane];
    half4 o = {(_Float16)(acc.x * dd + bb.x), (_Float16)(acc.y * dd + bb.y),
               (_Float16)(acc.z * dd + bb.z), (_Float16)(acc.w * dd + bb.w)};
    ((half4*)out)[(size_t)node * 32 + lane] = o;
}

// ---------------- BN stats stage a ----------------
__global__ __launch_bounds__(128) void k_stats_a(const _Float16* __restrict__ x,
                                                 float* __restrict__ part) {
    int blk = blockIdx.x;  // 512 blocks x 196 rows
    int f = threadIdx.x;   // 128
    int r0 = blk * 196, r1 = r0 + 196 < NN ? r0 + 196 : NN;
    float s = 0.f, s2 = 0.f;
    for (int r = r0; r < r1; r++) {
        float v = (float)x[(size_t)r * H + f];
        s += v; s2 += v * v;
    }
    part[blk * 256 + f] = s;
    part[blk * 256 + 128 + f] = s2;
}

// ---------------- BN stats stage b + scale/shift, fused ----------------
__global__ __launch_bounds__(256) void k_stats_bss(const float* __restrict__ part,
                                                   const float* __restrict__ gamma,
                                                   const float* __restrict__ beta,
                                                   float* __restrict__ ss) {
    __shared__ float sums[256];
    int c = threadIdx.x;  // 256
    float a = 0.f;
    for (int i = 0; i < 512; i++) a += part[i * 256 + c];
    sums[c] = a;
    __syncthreads();
    if (c < 128) {
        float mean = sums[c] * (1.0f / NN);
        float var  = sums[128 + c] * (1.0f / NN) - mean * mean;
        float sc   = gamma[c] * rsqrtf(var + 1e-5f);
        ss[c] = sc;
        ss[128 + c] = beta[c] - mean * sc;
    }
}

// ---------------- mean pool with fused BN+ReLU ----------------
__global__ __launch_bounds__(256) void k_pool2(const _Float16* __restrict__ x,
                                               const float* __restrict__ ss,
                                               const int* __restrict__ gstart,
                                               float* __restrict__ pooled) {
    int g = blockIdx.x;
    int beg = gstart[g], end = gstart[g + 1];
    int lane = threadIdx.x & 31;
    int walker = threadIdx.x >> 5;
    const half4* x4 = (const half4*)x;
    float4 sc = ((const float4*)ss)[lane];
    float4 sh = ((const float4*)(ss + 128))[lane];
    float4 acc = make_float4(0.f, 0.f, 0.f, 0.f);
    for (int r = beg + walker; r < end; r += 8) {
        half4 v = x4[(size_t)r * 32 + lane];
        acc.x += fmaxf((float)v.x * sc.x + sh.x, 0.f);
        acc.y += fmaxf((float)v.y * sc.y + sh.y, 0.f);
        acc.z += fmaxf((float)v.z * sc.z + sh.z, 0.f);
        acc.w += fmaxf((float)v.w * sc.w + sh.w, 0.f);
    }
    __shared__ float4 red[256];
    red[threadIdx.x] = acc;
    __syncthreads();
    if (threadIdx.x < 32) {
        float4 s = red[threadIdx.x];
        for (int w = 1; w < 8; w++) {
            float4 v = red[w * 32 + threadIdx.x];
            s.x += v.x; s.y += v.y; s.z += v.z; s.w += v.w;
        }
        float inv = 1.0f / fmaxf((float)(end - beg), 1.0f);
        ((float4*)pooled)[g * 32 + threadIdx.x] =
            make_float4(s.x * inv, s.y * inv, s.z * inv, s.w * inv);
    }
}

// ---------------- MLP head + log_softmax ----------------
__global__ __launch_bounds__(128) void k_head(const float* __restrict__ pooled,
                                              const float* __restrict__ w1, const float* __restrict__ b1,
                                              const float* __restrict__ w2, const float* __restrict__ b2,
                                              float* __restrict__ out) {
    __shared__ float p[H], hh[H], lg[NC], red;
    int g = blockIdx.x, f = threadIdx.x;
    p[f] = pooled[g * H + f];
    __syncthreads();
    float a = b1[f];
    for (int k = 0; k < H; k++) a += p[k] * w1[k * H + f];
    hh[f] = a > 0.f ? a : 0.f;
    __syncthreads();
    if (f < NC) {
        float l = b2[f];
        for (int k = 0; k < H; k++) l += hh[k] * w2[k * NC + f];
        lg[f] = l;
    }
    __syncthreads();
    if (f == 0) {
        float m = lg[0];
        for (int c = 1; c < NC; c++) m = m > lg[c] ? m : lg[c];
        float s = 0.f;
        for (int c = 0; c < NC; c++) s += expf(lg[c] - m);
        red = m + logf(s);
    }
    __syncthreads();
    if (f < NC) out[g * NC + f] = lg[f] - red;
}

extern "C" void kernel_launch(void* const* d_in, const int* in_sizes, int n_in,
                              void* d_out, int out_size, void* d_ws, size_t ws_size,
                              hipStream_t stream) {
    const float* x     = (const float*)d_in[0];
    const int*   ei    = (const int*)d_in[1];
    const int*   srcp  = ei;
    const int*   dstp  = ei + NE;
    const int*   batch = (const int*)d_in[2];
    const float* W[3]  = {(const float*)d_in[3],  (const float*)d_in[7],  (const float*)d_in[11]};
    const float* b[3]  = {(const float*)d_in[4],  (const float*)d_in[8],  (const float*)d_in[12]};
    const float* gm[3] = {(const float*)d_in[5],  (const float*)d_in[9],  (const float*)d_in[13]};
    const float* bt[3] = {(const float*)d_in[6],  (const float*)d_in[10], (const float*)d_in[14]};
    const float* w1 = (const float*)d_in[15];
    const float* b1 = (const float*)d_in[16];
    const float* w2 = (const float*)d_in[17];
    const float* b2 = (const float*)d_in[18];
    float* out = (float*)d_out;

    float* ws        = (float*)d_ws;
    float* dis       = ws;                          // 100000
    int*   deg_i     = (int*)(ws + 100000);         // 100000 (doubles as cursor)
    int*   rowptr    = (int*)(ws + 200000);         // 100004
    int*   partials  = (int*)(ws + 300004);         // 128
    int*   gstart    = (int*)(ws + 300132);         // 104
    int*   bcur      = (int*)(ws + 300236);         // 128
    float* ssbuf     = ws + 300364;                 // 768
    float* pooled    = ws + 301132;                 // 12800
    float* sp        = ws + 313932;                 // 131072 (stats partials)
    _Float16* wt     = (_Float16*)(ws + 445004);    // 3*16384 halves
    int*   col       = (int*)(ws + 469580);         // NE
    int2*  staging   = (int2*)(ws + 2069580);       // NE int2
    _Float16* aggh   = (_Float16*)(ws + 5269580);   // NN*H f16
    _Float16* hb     = (_Float16*)(ws + 11669580);  // NN*H f16

    const int nScanBlocks = (NN + 1023) / 1024;  // 98

    hipMemsetAsync(deg_i, 0, NN * sizeof(int), stream);
    k_deg<<<(NE + 255) / 256, 256, 0, stream>>>(dstp, deg_i);
    k_scan1<<<nScanBlocks, 256, 0, stream>>>(deg_i, rowptr, partials, dis);
    k_scan2g<<<2, 128, 0, stream>>>(partials, nScanBlocks, batch, gstart);
    k_scan3<<<(NN + 255) / 256, 256, 0, stream>>>(rowptr, partials, deg_i /*cursor*/, bcur);
    k_bucket1<<<(NE + 8191) / 8192, 256, 0, stream>>>(srcp, dstp, bcur, staging);
    k_bucket2<<<NB * 4, 256, 0, stream>>>(staging, rowptr, deg_i, col);
    k_prepw3<<<192, 256, 0, stream>>>(W[0], W[1], W[2], wt);

    const float* ss_prev = nullptr;
    for (int l = 0; l < 3; l++) {
        float* ss = ssbuf + l * 256;
        k_gemm<<<(NN + 63) / 64, 256, 0, stream>>>(l == 0 ? x : nullptr,
                                                   l == 0 ? nullptr : aggh,
                                                   ss_prev, wt + l * 16384, dis, hb);
        k_agg<<<NN / 8, 256, 0, stream>>>(hb, rowptr, col, dis, b[l], aggh);
        k_stats_a<<<512, 128, 0, stream>>>(aggh, sp);
        k_stats_bss<<<1, 256, 0, stream>>>(sp, gm[l], bt[l], ss);
        ss_prev = ss;
    }

    k_pool2<<<NG, 256, 0, stream>>>(aggh, ssbuf + 2 * 256, gstart, pooled);
    k_head<<<NG, 128, 0, stream>>>(pooled, w1, b1, w2, b2, out);
}